// Round 1
// baseline (559.077 us; speedup 1.0000x reference)
//
#include <hip/hip_runtime.h>

#define NODES 100000
#define EDGES 1600000

// ---------------------------------------------------------------------------
// CSR build: count -> 3-kernel exclusive scan -> cursor fill
// ---------------------------------------------------------------------------

__global__ __launch_bounds__(256) void count_kernel(const int* __restrict__ col,
                                                    int* __restrict__ cnt) {
    int e = blockIdx.x * 256 + threadIdx.x;
    if (e < EDGES) atomicAdd(&cnt[col[e]], 1);
}

__global__ __launch_bounds__(256) void dis_kernel(const int* __restrict__ cnt,
                                                  float* __restrict__ dis) {
    int i = blockIdx.x * 256 + threadIdx.x;
    if (i < NODES) dis[i] = rsqrtf((float)(cnt[i] + 1));  // +1 self-loop; always > 0
}

__global__ __launch_bounds__(1024) void scan_reduce(const int* __restrict__ cnt,
                                                    int* __restrict__ bsum) {
    __shared__ int s[1024];
    int t = threadIdx.x;
    int i = blockIdx.x * 1024 + t;
    s[t] = (i < NODES) ? cnt[i] : 0;
    __syncthreads();
    for (int d = 512; d > 0; d >>= 1) {
        if (t < d) s[t] += s[t + d];
        __syncthreads();
    }
    if (t == 0) bsum[blockIdx.x] = s[0];
}

__global__ __launch_bounds__(128) void scan_sums(int* __restrict__ bsum, int nb) {
    __shared__ int s[128];
    int t = threadIdx.x;
    int v = (t < nb) ? bsum[t] : 0;
    s[t] = v;
    __syncthreads();
    for (int d = 1; d < 128; d <<= 1) {
        int x = (t >= d) ? s[t - d] : 0;
        __syncthreads();
        s[t] += x;
        __syncthreads();
    }
    if (t < nb) bsum[t] = s[t] - v;  // exclusive block offsets
}

__global__ __launch_bounds__(1024) void scan_write(const int* __restrict__ cnt,
                                                   const int* __restrict__ boff,
                                                   int* __restrict__ row_start) {
    __shared__ int s[1024];
    int t = threadIdx.x;
    int i = blockIdx.x * 1024 + t;
    int v = (i < NODES) ? cnt[i] : 0;
    s[t] = v;
    __syncthreads();
    for (int d = 1; d < 1024; d <<= 1) {
        int x = (t >= d) ? s[t - d] : 0;
        __syncthreads();
        s[t] += x;
        __syncthreads();
    }
    if (i < NODES) row_start[i] = boff[blockIdx.x] + s[t] - v;  // exclusive
    if (i == 0) row_start[NODES] = EDGES;
}

__global__ __launch_bounds__(256) void fill_kernel(const int* __restrict__ row,
                                                   const int* __restrict__ col,
                                                   const int* __restrict__ row_start,
                                                   int* __restrict__ cursor,
                                                   int* __restrict__ edge_src) {
    int e = blockIdx.x * 256 + threadIdx.x;
    if (e < EDGES) {
        int c = col[e];
        int pos = row_start[c] + atomicAdd(&cursor[c], 1);
        edge_src[pos] = row[e];
    }
}

// ---------------------------------------------------------------------------
// GEMM:  H[r][:] = (X[r][:] @ W) * dis[r]      K = 128, NCOL in {128, 64}
// Block = 256 threads = 16 rows x 16 col-groups; W chunked 64xNCOL in LDS.
// ---------------------------------------------------------------------------

template <int NCOL>
__global__ __launch_bounds__(256) void gemm_scale(const float* __restrict__ X,
                                                  const float* __restrict__ W,
                                                  const float* __restrict__ dis,
                                                  float* __restrict__ H) {
    __shared__ float Xs[16][128];
    __shared__ float Ws[64][NCOL];
    const int tid = threadIdx.x;
    const int rowBase = blockIdx.x * 16;

    // stage X tile: 16x128 = 2048 floats = 512 float4
    {
        const float4* X4 = (const float4*)(X + (size_t)rowBase * 128);
        float4* Xs4 = (float4*)&Xs[0][0];
        Xs4[tid] = X4[tid];
        Xs4[tid + 256] = X4[tid + 256];
    }

    constexpr int CPT = NCOL / 16;  // cols per thread: 8 (NCOL=128) or 4 (NCOL=64)
    const int r = tid >> 4;
    const int cg = tid & 15;
    float acc[CPT];
#pragma unroll
    for (int j = 0; j < CPT; j++) acc[j] = 0.f;

    for (int kc = 0; kc < 128; kc += 64) {
        __syncthreads();
        // stage W chunk: 64 x NCOL floats
        constexpr int WV = 64 * NCOL / (256 * 4);
        const float4* W4 = (const float4*)(W + (size_t)kc * NCOL);
        float4* Ws4 = (float4*)&Ws[0][0];
#pragma unroll
        for (int i = 0; i < WV; i++) Ws4[tid + i * 256] = W4[tid + i * 256];
        __syncthreads();

#pragma unroll 16
        for (int k = 0; k < 64; k++) {
            float xv = Xs[r][kc + k];
            const float4* wrow = (const float4*)&Ws[k][cg * CPT];
#pragma unroll
            for (int j4 = 0; j4 < CPT / 4; j4++) {
                float4 wv = wrow[j4];
                acc[j4 * 4 + 0] += xv * wv.x;
                acc[j4 * 4 + 1] += xv * wv.y;
                acc[j4 * 4 + 2] += xv * wv.z;
                acc[j4 * 4 + 3] += xv * wv.w;
            }
        }
    }

    const float s = dis[rowBase + r];
    float4* out4 = (float4*)(H + (size_t)(rowBase + r) * NCOL + cg * CPT);
#pragma unroll
    for (int j4 = 0; j4 < CPT / 4; j4++) {
        float4 o;
        o.x = acc[j4 * 4 + 0] * s;
        o.y = acc[j4 * 4 + 1] * s;
        o.z = acc[j4 * 4 + 2] * s;
        o.w = acc[j4 * 4 + 3] * s;
        out4[j4] = o;
    }
}

// ---------------------------------------------------------------------------
// Aggregation: OUT[v] = act( dis[v] * (sum_{e in CSR(v)} H[src(e)] + H[v]) + b )
// One wave per node. C=128: float2/lane (512B rows). C=64: float/lane (256B).
// ---------------------------------------------------------------------------

template <int C, bool RELU>
__global__ __launch_bounds__(256) void agg_kernel(const float* __restrict__ H,
                                                  const int* __restrict__ row_start,
                                                  const int* __restrict__ edge_src,
                                                  const float* __restrict__ dis,
                                                  const float* __restrict__ bias,
                                                  float* __restrict__ OUT) {
    const int wave = threadIdx.x >> 6;
    const int lane = threadIdx.x & 63;
    const int v = blockIdx.x * 4 + wave;
    if (v >= NODES) return;

    const int e0 = row_start[v];
    const int e1 = row_start[v + 1];

    if constexpr (C == 128) {
        const float2* Hv = (const float2*)(H + (size_t)v * 128) + lane;
        float2 a = *Hv;  // self-loop contribution
        float ax = a.x, ay = a.y;
        int e = e0;
        for (; e + 4 <= e1; e += 4) {
            int s0 = edge_src[e + 0];
            int s1 = edge_src[e + 1];
            int s2 = edge_src[e + 2];
            int s3 = edge_src[e + 3];
            float2 m0 = *((const float2*)(H + (size_t)s0 * 128) + lane);
            float2 m1 = *((const float2*)(H + (size_t)s1 * 128) + lane);
            float2 m2 = *((const float2*)(H + (size_t)s2 * 128) + lane);
            float2 m3 = *((const float2*)(H + (size_t)s3 * 128) + lane);
            ax += m0.x + m1.x + m2.x + m3.x;
            ay += m0.y + m1.y + m2.y + m3.y;
        }
        for (; e < e1; e++) {
            int s = edge_src[e];
            float2 m = *((const float2*)(H + (size_t)s * 128) + lane);
            ax += m.x;
            ay += m.y;
        }
        const float d = dis[v];
        const float2 b = *((const float2*)bias + lane);
        float ox = ax * d + b.x;
        float oy = ay * d + b.y;
        if constexpr (RELU) {
            ox = fmaxf(ox, 0.f);
            oy = fmaxf(oy, 0.f);
        }
        float2 o;
        o.x = ox;
        o.y = oy;
        *((float2*)(OUT + (size_t)v * 128) + lane) = o;
    } else {
        const float* Hv = H + (size_t)v * 64 + lane;
        float a = *Hv;  // self-loop
        int e = e0;
        for (; e + 4 <= e1; e += 4) {
            int s0 = edge_src[e + 0];
            int s1 = edge_src[e + 1];
            int s2 = edge_src[e + 2];
            int s3 = edge_src[e + 3];
            float m0 = H[(size_t)s0 * 64 + lane];
            float m1 = H[(size_t)s1 * 64 + lane];
            float m2 = H[(size_t)s2 * 64 + lane];
            float m3 = H[(size_t)s3 * 64 + lane];
            a += m0 + m1 + m2 + m3;
        }
        for (; e < e1; e++) {
            a += H[(size_t)edge_src[e] * 64 + lane];
        }
        float o = a * dis[v] + bias[lane];
        if constexpr (RELU) o = fmaxf(o, 0.f);
        OUT[(size_t)v * 64 + lane] = o;
    }
}

// ---------------------------------------------------------------------------

extern "C" void kernel_launch(void* const* d_in, const int* in_sizes, int n_in,
                              void* d_out, int out_size, void* d_ws, size_t ws_size,
                              hipStream_t stream) {
    const float* x   = (const float*)d_in[0];
    const int* eidx  = (const int*)d_in[1];
    const float* W1  = (const float*)d_in[2];
    const float* b1  = (const float*)d_in[3];
    const float* W2  = (const float*)d_in[4];
    const float* b2  = (const float*)d_in[5];
    float* out = (float*)d_out;

    const int* erow = eidx;          // sources
    const int* ecol = eidx + EDGES;  // targets

    // workspace carve-up (256B aligned)
    char* w = (char*)d_ws;
    size_t off = 0;
    auto alloc = [&](size_t bytes) -> void* {
        void* p = w + off;
        off += (bytes + 255) & ~(size_t)255;
        return p;
    };
    int*   deg_cnt = (int*)alloc((size_t)NODES * 4);
    float* dis     = (float*)alloc((size_t)NODES * 4);
    int*   cursor  = (int*)alloc((size_t)NODES * 4);
    int*   rowst   = (int*)alloc((size_t)(NODES + 1) * 4);
    int*   esrc    = (int*)alloc((size_t)EDGES * 4);
    int*   bsum    = (int*)alloc(128 * 4);
    float* bufA    = (float*)alloc((size_t)NODES * 128 * 4);  // h1' then h2'
    float* bufB    = (float*)alloc((size_t)NODES * 128 * 4);  // relu(out1)

    hipMemsetAsync(deg_cnt, 0, (size_t)NODES * 4, stream);
    hipMemsetAsync(cursor, 0, (size_t)NODES * 4, stream);

    const int NB = (NODES + 1023) / 1024;  // 98

    count_kernel<<<(EDGES + 255) / 256, 256, 0, stream>>>(ecol, deg_cnt);
    dis_kernel<<<(NODES + 255) / 256, 256, 0, stream>>>(deg_cnt, dis);
    scan_reduce<<<NB, 1024, 0, stream>>>(deg_cnt, bsum);
    scan_sums<<<1, 128, 0, stream>>>(bsum, NB);
    scan_write<<<NB, 1024, 0, stream>>>(deg_cnt, bsum, rowst);
    fill_kernel<<<(EDGES + 255) / 256, 256, 0, stream>>>(erow, ecol, rowst, cursor, esrc);

    // layer 1: h1' = (x @ W1) * dis[row] ; out1 = relu(dis[col]*(agg + self) + b1)
    gemm_scale<128><<<NODES / 16, 256, 0, stream>>>(x, W1, dis, bufA);
    agg_kernel<128, true><<<(NODES + 3) / 4, 256, 0, stream>>>(bufA, rowst, esrc, dis, b1, bufB);

    // layer 2: h2' = (out1 @ W2) * dis[row] ; out = dis[col]*(agg + self) + b2
    gemm_scale<64><<<NODES / 16, 256, 0, stream>>>(bufB, W2, dis, bufA);
    agg_kernel<64, false><<<(NODES + 3) / 4, 256, 0, stream>>>(bufA, rowst, esrc, dis, b2, out);
}

// Round 2
// 419.702 us; speedup vs baseline: 1.3321x; 1.3321x over previous
//
#include <hip/hip_runtime.h>

#define NODES 100000
#define EDGES 1600000

typedef __attribute__((ext_vector_type(8))) short short8;
typedef __attribute__((ext_vector_type(4))) float f32x4;

// ---------------------------------------------------------------------------
// bf16 helpers (RNE)
// ---------------------------------------------------------------------------
__device__ inline unsigned short f2bf(float f) {
    unsigned u = __builtin_bit_cast(unsigned, f);
    u = u + 0x7fff + ((u >> 16) & 1);
    return (unsigned short)(u >> 16);
}
__device__ inline float bf2f(unsigned short h) {
    unsigned u = ((unsigned)h) << 16;
    return __builtin_bit_cast(float, u);
}

// ---------------------------------------------------------------------------
// CSR build: count -> 3-kernel exclusive scan -> cursor fill
// ---------------------------------------------------------------------------

__global__ __launch_bounds__(256) void count_kernel(const int* __restrict__ col,
                                                    int* __restrict__ cnt) {
    int e = blockIdx.x * 256 + threadIdx.x;
    if (e < EDGES) atomicAdd(&cnt[col[e]], 1);
}

__global__ __launch_bounds__(256) void dis_kernel(const int* __restrict__ cnt,
                                                  float* __restrict__ dis) {
    int i = blockIdx.x * 256 + threadIdx.x;
    if (i < NODES) dis[i] = rsqrtf((float)(cnt[i] + 1));  // +1 self-loop
}

__global__ __launch_bounds__(1024) void scan_reduce(const int* __restrict__ cnt,
                                                    int* __restrict__ bsum) {
    __shared__ int s[1024];
    int t = threadIdx.x;
    int i = blockIdx.x * 1024 + t;
    s[t] = (i < NODES) ? cnt[i] : 0;
    __syncthreads();
    for (int d = 512; d > 0; d >>= 1) {
        if (t < d) s[t] += s[t + d];
        __syncthreads();
    }
    if (t == 0) bsum[blockIdx.x] = s[0];
}

__global__ __launch_bounds__(128) void scan_sums(int* __restrict__ bsum, int nb) {
    __shared__ int s[128];
    int t = threadIdx.x;
    int v = (t < nb) ? bsum[t] : 0;
    s[t] = v;
    __syncthreads();
    for (int d = 1; d < 128; d <<= 1) {
        int x = (t >= d) ? s[t - d] : 0;
        __syncthreads();
        s[t] += x;
        __syncthreads();
    }
    if (t < nb) bsum[t] = s[t] - v;  // exclusive block offsets
}

__global__ __launch_bounds__(1024) void scan_write(const int* __restrict__ cnt,
                                                   const int* __restrict__ boff,
                                                   int* __restrict__ row_start) {
    __shared__ int s[1024];
    int t = threadIdx.x;
    int i = blockIdx.x * 1024 + t;
    int v = (i < NODES) ? cnt[i] : 0;
    s[t] = v;
    __syncthreads();
    for (int d = 1; d < 1024; d <<= 1) {
        int x = (t >= d) ? s[t - d] : 0;
        __syncthreads();
        s[t] += x;
        __syncthreads();
    }
    if (i < NODES) row_start[i] = boff[blockIdx.x] + s[t] - v;  // exclusive
    if (i == 0) row_start[NODES] = EDGES;
}

__global__ __launch_bounds__(256) void fill_kernel(const int* __restrict__ row,
                                                   const int* __restrict__ col,
                                                   const int* __restrict__ row_start,
                                                   int* __restrict__ cursor,
                                                   int* __restrict__ edge_src) {
    int e = blockIdx.x * 256 + threadIdx.x;
    if (e < EDGES) {
        int c = col[e];
        int pos = row_start[c] + atomicAdd(&cursor[c], 1);
        edge_src[pos] = row[e];
    }
}

// ---------------------------------------------------------------------------
// W prep: split f32 W[K=128][NCOL] into hi/lo bf16, fragment-major layout:
//   wpack[kt][ct][lane][i]  with  k = kt*32 + (lane>>4)*8 + i,  c = ct*16 + (lane&15)
// so a B-fragment is one contiguous 16B ds_read_b128 per lane.
// ---------------------------------------------------------------------------

template <int NCOL>
__global__ __launch_bounds__(256) void w_prep(const float* __restrict__ W,
                                              unsigned short* __restrict__ wh,
                                              unsigned short* __restrict__ wl) {
    constexpr int NCT = NCOL / 16;
    constexpr int FRAGS = 4 * NCT * 64;
    int idx = blockIdx.x * 256 + threadIdx.x;
    if (idx >= FRAGS) return;
    int lane = idx & 63;
    int rem = idx >> 6;
    int ct = rem % NCT;
    int kt = rem / NCT;
    int kbase = kt * 32 + ((lane >> 4) * 8);
    int c = ct * 16 + (lane & 15);
#pragma unroll
    for (int i = 0; i < 8; i++) {
        float v = W[(size_t)(kbase + i) * NCOL + c];
        unsigned short hi = f2bf(v);
        unsigned short lo = f2bf(v - bf2f(hi));
        wh[(size_t)idx * 8 + i] = hi;
        wl[(size_t)idx * 8 + i] = lo;
    }
}

// ---------------------------------------------------------------------------
// GEMM via MFMA 16x16x32 bf16, split-precision (xh@Wh + xl@Wh + xh@Wl):
//   H[r][:] = (X[r][:] @ W) * dis[r]
// 512 threads = 8 waves, each wave does 16 rows x NCOL. W (packed hi/lo) in LDS
// via global_load_lds; A-frags loaded straight from global (k-contiguous).
// ---------------------------------------------------------------------------

template <int NCOL>
__global__ __launch_bounds__(512) void gemm_mfma(const float* __restrict__ X,
                                                 const unsigned short* __restrict__ wh,
                                                 const unsigned short* __restrict__ wl,
                                                 const float* __restrict__ dis,
                                                 float* __restrict__ H) {
    constexpr int NCT = NCOL / 16;
    constexpr int FRAGS = 4 * NCT * 64;  // 2048 (NCOL=128) or 1024 (NCOL=64)
    __shared__ unsigned short s_wh[FRAGS * 8];
    __shared__ unsigned short s_wl[FRAGS * 8];

    const int tid = threadIdx.x;
    const int wave = tid >> 6;
    const int lane = tid & 63;

    const int row0 = blockIdx.x * 128 + wave * 16 + (lane & 15);
    const bool active = (blockIdx.x * 128 + wave * 16) < NODES;  // wave-uniform

    // prefetch A: per ktile, lane reads 8 contiguous floats (2x float4)
    float4 xa[4], xb[4];
    if (active) {
        const float* xrow = X + (size_t)row0 * 128 + ((lane >> 4) * 8);
#pragma unroll
        for (int kt = 0; kt < 4; kt++) {
            xa[kt] = *(const float4*)(xrow + kt * 32);
            xb[kt] = *(const float4*)(xrow + kt * 32 + 4);
        }
    }

    // stage packed W into LDS (linear, 16B per lane per round)
    constexpr int ROUNDS = (FRAGS * 16) / (512 * 16);  // 4 or 2
#pragma unroll
    for (int j = 0; j < ROUNDS; j++) {
        __builtin_amdgcn_global_load_lds((const unsigned int*)((const char*)wh + ((size_t)tid + j * 512) * 16),
                                         (unsigned int*)(s_wh + ((size_t)tid + j * 512) * 8), 16, 0, 0);
        __builtin_amdgcn_global_load_lds((const unsigned int*)((const char*)wl + ((size_t)tid + j * 512) * 16),
                                         (unsigned int*)(s_wl + ((size_t)tid + j * 512) * 8), 16, 0, 0);
    }
    __syncthreads();

    if (!active) return;

    // convert A to bf16 hi/lo fragments
    short8 ah[4], al[4];
#pragma unroll
    for (int kt = 0; kt < 4; kt++) {
        float xs[8] = {xa[kt].x, xa[kt].y, xa[kt].z, xa[kt].w,
                       xb[kt].x, xb[kt].y, xb[kt].z, xb[kt].w};
#pragma unroll
        for (int i = 0; i < 8; i++) {
            unsigned short hi = f2bf(xs[i]);
            unsigned short lo = f2bf(xs[i] - bf2f(hi));
            ah[kt][i] = (short)hi;
            al[kt][i] = (short)lo;
        }
    }

    f32x4 acc[NCT];
#pragma unroll
    for (int ct = 0; ct < NCT; ct++) acc[ct] = (f32x4){0.f, 0.f, 0.f, 0.f};

#pragma unroll
    for (int kt = 0; kt < 4; kt++) {
#pragma unroll
        for (int ct = 0; ct < NCT; ct++) {
            const int fo = ((kt * NCT + ct) * 64 + lane) * 8;
            short8 bh = *(const short8*)&s_wh[fo];
            short8 bl = *(const short8*)&s_wl[fo];
            acc[ct] = __builtin_amdgcn_mfma_f32_16x16x32_bf16(ah[kt], bh, acc[ct], 0, 0, 0);
            acc[ct] = __builtin_amdgcn_mfma_f32_16x16x32_bf16(al[kt], bh, acc[ct], 0, 0, 0);
            acc[ct] = __builtin_amdgcn_mfma_f32_16x16x32_bf16(ah[kt], bl, acc[ct], 0, 0, 0);
        }
    }

    // D layout: col = lane&15, row = (lane>>4)*4 + reg
    const int rbase = blockIdx.x * 128 + wave * 16 + ((lane >> 4) * 4);
    float d[4];
#pragma unroll
    for (int r = 0; r < 4; r++) d[r] = dis[rbase + r];
#pragma unroll
    for (int ct = 0; ct < NCT; ct++) {
#pragma unroll
        for (int r = 0; r < 4; r++) {
            H[(size_t)(rbase + r) * NCOL + ct * 16 + (lane & 15)] = acc[ct][r] * d[r];
        }
    }
}

// ---------------------------------------------------------------------------
// Aggregation: OUT[v] = act( dis[v] * (sum_{e in CSR(v)} H[src(e)] + H[v]) + b )
// One wave per node. C=128: float2/lane (512B rows). C=64: float/lane (256B).
// ---------------------------------------------------------------------------

template <int C, bool RELU>
__global__ __launch_bounds__(256) void agg_kernel(const float* __restrict__ H,
                                                  const int* __restrict__ row_start,
                                                  const int* __restrict__ edge_src,
                                                  const float* __restrict__ dis,
                                                  const float* __restrict__ bias,
                                                  float* __restrict__ OUT) {
    const int wave = threadIdx.x >> 6;
    const int lane = threadIdx.x & 63;
    const int v = blockIdx.x * 4 + wave;
    if (v >= NODES) return;

    const int e0 = row_start[v];
    const int e1 = row_start[v + 1];

    if constexpr (C == 128) {
        const float2* Hv = (const float2*)(H + (size_t)v * 128) + lane;
        float2 a = *Hv;  // self-loop contribution
        float ax = a.x, ay = a.y;
        int e = e0;
        for (; e + 4 <= e1; e += 4) {
            int s0 = edge_src[e + 0];
            int s1 = edge_src[e + 1];
            int s2 = edge_src[e + 2];
            int s3 = edge_src[e + 3];
            float2 m0 = *((const float2*)(H + (size_t)s0 * 128) + lane);
            float2 m1 = *((const float2*)(H + (size_t)s1 * 128) + lane);
            float2 m2 = *((const float2*)(H + (size_t)s2 * 128) + lane);
            float2 m3 = *((const float2*)(H + (size_t)s3 * 128) + lane);
            ax += m0.x + m1.x + m2.x + m3.x;
            ay += m0.y + m1.y + m2.y + m3.y;
        }
        for (; e < e1; e++) {
            int s = edge_src[e];
            float2 m = *((const float2*)(H + (size_t)s * 128) + lane);
            ax += m.x;
            ay += m.y;
        }
        const float d = dis[v];
        const float2 b = *((const float2*)bias + lane);
        float ox = ax * d + b.x;
        float oy = ay * d + b.y;
        if constexpr (RELU) {
            ox = fmaxf(ox, 0.f);
            oy = fmaxf(oy, 0.f);
        }
        float2 o;
        o.x = ox;
        o.y = oy;
        *((float2*)(OUT + (size_t)v * 128) + lane) = o;
    } else {
        const float* Hv = H + (size_t)v * 64 + lane;
        float a = *Hv;  // self-loop
        int e = e0;
        for (; e + 4 <= e1; e += 4) {
            int s0 = edge_src[e + 0];
            int s1 = edge_src[e + 1];
            int s2 = edge_src[e + 2];
            int s3 = edge_src[e + 3];
            float m0 = H[(size_t)s0 * 64 + lane];
            float m1 = H[(size_t)s1 * 64 + lane];
            float m2 = H[(size_t)s2 * 64 + lane];
            float m3 = H[(size_t)s3 * 64 + lane];
            a += m0 + m1 + m2 + m3;
        }
        for (; e < e1; e++) {
            a += H[(size_t)edge_src[e] * 64 + lane];
        }
        float o = a * dis[v] + bias[lane];
        if constexpr (RELU) o = fmaxf(o, 0.f);
        OUT[(size_t)v * 64 + lane] = o;
    }
}

// ---------------------------------------------------------------------------

extern "C" void kernel_launch(void* const* d_in, const int* in_sizes, int n_in,
                              void* d_out, int out_size, void* d_ws, size_t ws_size,
                              hipStream_t stream) {
    const float* x   = (const float*)d_in[0];
    const int* eidx  = (const int*)d_in[1];
    const float* W1  = (const float*)d_in[2];
    const float* b1  = (const float*)d_in[3];
    const float* W2  = (const float*)d_in[4];
    const float* b2  = (const float*)d_in[5];
    float* out = (float*)d_out;

    const int* erow = eidx;          // sources
    const int* ecol = eidx + EDGES;  // targets

    // workspace carve-up (256B aligned)
    char* w = (char*)d_ws;
    size_t off = 0;
    auto alloc = [&](size_t bytes) -> void* {
        void* p = w + off;
        off += (bytes + 255) & ~(size_t)255;
        return p;
    };
    int*   deg_cnt = (int*)alloc((size_t)NODES * 4);
    float* dis     = (float*)alloc((size_t)NODES * 4);
    int*   cursor  = (int*)alloc((size_t)NODES * 4);
    int*   rowst   = (int*)alloc((size_t)(NODES + 1) * 4);
    int*   esrc    = (int*)alloc((size_t)EDGES * 4);
    int*   bsum    = (int*)alloc(128 * 4);
    unsigned short* wh1 = (unsigned short*)alloc(2048 * 8 * 2);
    unsigned short* wl1 = (unsigned short*)alloc(2048 * 8 * 2);
    unsigned short* wh2 = (unsigned short*)alloc(1024 * 8 * 2);
    unsigned short* wl2 = (unsigned short*)alloc(1024 * 8 * 2);
    float* bufA    = (float*)alloc((size_t)NODES * 128 * 4);  // h1' then h2'
    float* bufB    = (float*)alloc((size_t)NODES * 128 * 4);  // relu(out1)

    hipMemsetAsync(deg_cnt, 0, (size_t)NODES * 4, stream);
    hipMemsetAsync(cursor, 0, (size_t)NODES * 4, stream);

    const int NB = (NODES + 1023) / 1024;  // 98

    count_kernel<<<(EDGES + 255) / 256, 256, 0, stream>>>(ecol, deg_cnt);
    dis_kernel<<<(NODES + 255) / 256, 256, 0, stream>>>(deg_cnt, dis);
    scan_reduce<<<NB, 1024, 0, stream>>>(deg_cnt, bsum);
    scan_sums<<<1, 128, 0, stream>>>(bsum, NB);
    scan_write<<<NB, 1024, 0, stream>>>(deg_cnt, bsum, rowst);
    fill_kernel<<<(EDGES + 255) / 256, 256, 0, stream>>>(erow, ecol, rowst, cursor, esrc);

    w_prep<128><<<8, 256, 0, stream>>>(W1, wh1, wl1);
    w_prep<64><<<4, 256, 0, stream>>>(W2, wh2, wl2);

    const int GB = (NODES + 127) / 128;  // 782

    // layer 1: h1' = (x @ W1) * dis[row] ; out1 = relu(dis[col]*(agg + self) + b1)
    gemm_mfma<128><<<GB, 512, 0, stream>>>(x, wh1, wl1, dis, bufA);
    agg_kernel<128, true><<<(NODES + 3) / 4, 256, 0, stream>>>(bufA, rowst, esrc, dis, b1, bufB);

    // layer 2: h2' = (out1 @ W2) * dis[row] ; out = dis[col]*(agg + self) + b2
    gemm_mfma<64><<<GB, 512, 0, stream>>>(bufB, wh2, wl2, dis, bufA);
    agg_kernel<64, false><<<(NODES + 3) / 4, 256, 0, stream>>>(bufA, rowst, esrc, dis, b2, out);
}

// Round 3
// 360.309 us; speedup vs baseline: 1.5517x; 1.1648x over previous
//
#include <hip/hip_runtime.h>
#include <hip/hip_fp16.h>

#define NODES 100000
#define EDGES 1600000

typedef __attribute__((ext_vector_type(8))) short short8;
typedef __attribute__((ext_vector_type(4))) float f32x4;

// ---------------------------------------------------------------------------
// bf16 / fp16 helpers
// ---------------------------------------------------------------------------
__device__ inline unsigned short f2bf(float f) {
    unsigned u = __builtin_bit_cast(unsigned, f);
    u = u + 0x7fff + ((u >> 16) & 1);
    return (unsigned short)(u >> 16);
}
__device__ inline float bf2f(unsigned short h) {
    unsigned u = ((unsigned)h) << 16;
    return __builtin_bit_cast(float, u);
}
__device__ inline unsigned short f2h_bits(float f) {
    __half h = __float2half_rn(f);
    return __builtin_bit_cast(unsigned short, h);
}
__device__ inline float h2f(unsigned short bits) {
    return __half2float(__builtin_bit_cast(__half, bits));
}
__device__ inline float2 h2f2(unsigned int bits) {
    __half2 h = __builtin_bit_cast(__half2, bits);
    return __half22float2(h);
}

// ---------------------------------------------------------------------------
// CSR build: count -> 3-kernel exclusive scan -> cursor fill
// ---------------------------------------------------------------------------

__global__ __launch_bounds__(256) void count_kernel(const int* __restrict__ col,
                                                    int* __restrict__ cnt) {
    int e = blockIdx.x * 256 + threadIdx.x;
    if (e < EDGES) atomicAdd(&cnt[col[e]], 1);
}

__global__ __launch_bounds__(256) void dis_kernel(const int* __restrict__ cnt,
                                                  float* __restrict__ dis) {
    int i = blockIdx.x * 256 + threadIdx.x;
    if (i < NODES) dis[i] = rsqrtf((float)(cnt[i] + 1));  // +1 self-loop
}

__global__ __launch_bounds__(1024) void scan_reduce(const int* __restrict__ cnt,
                                                    int* __restrict__ bsum) {
    __shared__ int s[1024];
    int t = threadIdx.x;
    int i = blockIdx.x * 1024 + t;
    s[t] = (i < NODES) ? cnt[i] : 0;
    __syncthreads();
    for (int d = 512; d > 0; d >>= 1) {
        if (t < d) s[t] += s[t + d];
        __syncthreads();
    }
    if (t == 0) bsum[blockIdx.x] = s[0];
}

__global__ __launch_bounds__(128) void scan_sums(int* __restrict__ bsum, int nb) {
    __shared__ int s[128];
    int t = threadIdx.x;
    int v = (t < nb) ? bsum[t] : 0;
    s[t] = v;
    __syncthreads();
    for (int d = 1; d < 128; d <<= 1) {
        int x = (t >= d) ? s[t - d] : 0;
        __syncthreads();
        s[t] += x;
        __syncthreads();
    }
    if (t < nb) bsum[t] = s[t] - v;  // exclusive block offsets
}

__global__ __launch_bounds__(1024) void scan_write(const int* __restrict__ cnt,
                                                   const int* __restrict__ boff,
                                                   int* __restrict__ row_start) {
    __shared__ int s[1024];
    int t = threadIdx.x;
    int i = blockIdx.x * 1024 + t;
    int v = (i < NODES) ? cnt[i] : 0;
    s[t] = v;
    __syncthreads();
    for (int d = 1; d < 1024; d <<= 1) {
        int x = (t >= d) ? s[t - d] : 0;
        __syncthreads();
        s[t] += x;
        __syncthreads();
    }
    if (i < NODES) row_start[i] = boff[blockIdx.x] + s[t] - v;  // exclusive
    if (i == 0) row_start[NODES] = EDGES;
}

__global__ __launch_bounds__(256) void fill_kernel(const int* __restrict__ row,
                                                   const int* __restrict__ col,
                                                   const int* __restrict__ row_start,
                                                   int* __restrict__ cursor,
                                                   int* __restrict__ edge_src) {
    int e = blockIdx.x * 256 + threadIdx.x;
    if (e < EDGES) {
        int c = col[e];
        int pos = row_start[c] + atomicAdd(&cursor[c], 1);
        edge_src[pos] = row[e];
    }
}

// ---------------------------------------------------------------------------
// W prep: split f32 W[K=128][NCOL] into hi/lo bf16, fragment-major layout:
//   k = kt*32 + (lane>>4)*8 + i,  c = ct*16 + (lane&15)
// ---------------------------------------------------------------------------

template <int NCOL>
__global__ __launch_bounds__(256) void w_prep(const float* __restrict__ W,
                                              unsigned short* __restrict__ wh,
                                              unsigned short* __restrict__ wl) {
    constexpr int NCT = NCOL / 16;
    constexpr int FRAGS = 4 * NCT * 64;
    int idx = blockIdx.x * 256 + threadIdx.x;
    if (idx >= FRAGS) return;
    int lane = idx & 63;
    int rem = idx >> 6;
    int ct = rem % NCT;
    int kt = rem / NCT;
    int kbase = kt * 32 + ((lane >> 4) * 8);
    int c = ct * 16 + (lane & 15);
#pragma unroll
    for (int i = 0; i < 8; i++) {
        float v = W[(size_t)(kbase + i) * NCOL + c];
        unsigned short hi = f2bf(v);
        unsigned short lo = f2bf(v - bf2f(hi));
        wh[(size_t)idx * 8 + i] = hi;
        wl[(size_t)idx * 8 + i] = lo;
    }
}

// ---------------------------------------------------------------------------
// GEMM via MFMA 16x16x32 bf16, split-precision (xh@Wh + xl@Wh + xh@Wl):
//   H[r][:] = (X[r][:] @ W) * dis[r]
// IN_HALF: X is fp16 (exact bf16 hi/lo split). Output H is fp16.
// ---------------------------------------------------------------------------

template <int NCOL, bool IN_HALF>
__global__ __launch_bounds__(512) void gemm_mfma(const void* __restrict__ Xv,
                                                 const unsigned short* __restrict__ wh,
                                                 const unsigned short* __restrict__ wl,
                                                 const float* __restrict__ dis,
                                                 unsigned short* __restrict__ H) {
    constexpr int NCT = NCOL / 16;
    constexpr int FRAGS = 4 * NCT * 64;  // 2048 (NCOL=128) or 1024 (NCOL=64)
    __shared__ unsigned short s_wh[FRAGS * 8];
    __shared__ unsigned short s_wl[FRAGS * 8];

    const int tid = threadIdx.x;
    const int wave = tid >> 6;
    const int lane = tid & 63;

    const int row0 = blockIdx.x * 128 + wave * 16 + (lane & 15);
    const bool active = (blockIdx.x * 128 + wave * 16) < NODES;  // wave-uniform

    // prefetch A: per ktile, lane reads 8 contiguous elements of its row
    float xs[4][8];
    if (active) {
        if constexpr (IN_HALF) {
            const unsigned short* xrow = (const unsigned short*)Xv + (size_t)row0 * 128 + ((lane >> 4) * 8);
#pragma unroll
            for (int kt = 0; kt < 4; kt++) {
                short8 raw = *(const short8*)(xrow + kt * 32);
#pragma unroll
                for (int i = 0; i < 8; i++) xs[kt][i] = h2f((unsigned short)raw[i]);
            }
        } else {
            const float* xrow = (const float*)Xv + (size_t)row0 * 128 + ((lane >> 4) * 8);
#pragma unroll
            for (int kt = 0; kt < 4; kt++) {
                float4 a = *(const float4*)(xrow + kt * 32);
                float4 b = *(const float4*)(xrow + kt * 32 + 4);
                xs[kt][0] = a.x; xs[kt][1] = a.y; xs[kt][2] = a.z; xs[kt][3] = a.w;
                xs[kt][4] = b.x; xs[kt][5] = b.y; xs[kt][6] = b.z; xs[kt][7] = b.w;
            }
        }
    }

    // stage packed W into LDS (linear, 16B per lane per round)
    constexpr int ROUNDS = (FRAGS * 16) / (512 * 16);  // 4 or 2
#pragma unroll
    for (int j = 0; j < ROUNDS; j++) {
        __builtin_amdgcn_global_load_lds((const unsigned int*)((const char*)wh + ((size_t)tid + j * 512) * 16),
                                         (unsigned int*)(s_wh + ((size_t)tid + j * 512) * 8), 16, 0, 0);
        __builtin_amdgcn_global_load_lds((const unsigned int*)((const char*)wl + ((size_t)tid + j * 512) * 16),
                                         (unsigned int*)(s_wl + ((size_t)tid + j * 512) * 8), 16, 0, 0);
    }
    __syncthreads();

    if (!active) return;

    // convert A to bf16 hi/lo fragments
    short8 ah[4], al[4];
#pragma unroll
    for (int kt = 0; kt < 4; kt++) {
#pragma unroll
        for (int i = 0; i < 8; i++) {
            unsigned short hi = f2bf(xs[kt][i]);
            unsigned short lo = f2bf(xs[kt][i] - bf2f(hi));
            ah[kt][i] = (short)hi;
            al[kt][i] = (short)lo;
        }
    }

    f32x4 acc[NCT];
#pragma unroll
    for (int ct = 0; ct < NCT; ct++) acc[ct] = (f32x4){0.f, 0.f, 0.f, 0.f};

#pragma unroll
    for (int kt = 0; kt < 4; kt++) {
#pragma unroll
        for (int ct = 0; ct < NCT; ct++) {
            const int fo = ((kt * NCT + ct) * 64 + lane) * 8;
            short8 bh = *(const short8*)&s_wh[fo];
            short8 bl = *(const short8*)&s_wl[fo];
            acc[ct] = __builtin_amdgcn_mfma_f32_16x16x32_bf16(ah[kt], bh, acc[ct], 0, 0, 0);
            acc[ct] = __builtin_amdgcn_mfma_f32_16x16x32_bf16(al[kt], bh, acc[ct], 0, 0, 0);
            acc[ct] = __builtin_amdgcn_mfma_f32_16x16x32_bf16(ah[kt], bl, acc[ct], 0, 0, 0);
        }
    }

    // D layout: col = lane&15, row = (lane>>4)*4 + reg
    const int rbase = blockIdx.x * 128 + wave * 16 + ((lane >> 4) * 4);
    float d[4];
#pragma unroll
    for (int r = 0; r < 4; r++) d[r] = dis[rbase + r];
#pragma unroll
    for (int ct = 0; ct < NCT; ct++) {
#pragma unroll
        for (int r = 0; r < 4; r++) {
            H[(size_t)(rbase + r) * NCOL + ct * 16 + (lane & 15)] = f2h_bits(acc[ct][r] * d[r]);
        }
    }
}

// ---------------------------------------------------------------------------
// Aggregation (fp16 H): OUT[v] = act( dis[v]*(sum_{CSR(v)} H[src] + H[v]) + b )
// One wave per node, 8-deep edge unroll, edge indices via readlane (SGPR base).
// C=128: 4B/lane (half2). C=64: 2B/lane (half). OUT fp16 (layer1) or f32.
// ---------------------------------------------------------------------------

template <int C, bool RELU, bool OUT_HALF>
__global__ __launch_bounds__(256) void agg_kernel(const unsigned short* __restrict__ H,
                                                  const int* __restrict__ row_start,
                                                  const int* __restrict__ edge_src,
                                                  const float* __restrict__ dis,
                                                  const float* __restrict__ bias,
                                                  void* __restrict__ OUT) {
    const int wave = threadIdx.x >> 6;
    const int lane = threadIdx.x & 63;
    const int v = blockIdx.x * 4 + wave;
    if (v >= NODES) return;

    const int e0 = row_start[v];
    const int e1 = row_start[v + 1];

    if constexpr (C == 128) {
        float ax, ay;
        {
            unsigned self = ((const unsigned*)(H + (size_t)v * 128))[lane];
            float2 s2 = h2f2(self);
            ax = s2.x; ay = s2.y;
        }
        int e = e0;
        for (; e + 8 <= e1; e += 8) {
            int myidx = edge_src[e + (lane & 7)];
            int s0 = __builtin_amdgcn_readlane(myidx, 0);
            int s1 = __builtin_amdgcn_readlane(myidx, 1);
            int s2 = __builtin_amdgcn_readlane(myidx, 2);
            int s3 = __builtin_amdgcn_readlane(myidx, 3);
            int s4 = __builtin_amdgcn_readlane(myidx, 4);
            int s5 = __builtin_amdgcn_readlane(myidx, 5);
            int s6 = __builtin_amdgcn_readlane(myidx, 6);
            int s7 = __builtin_amdgcn_readlane(myidx, 7);
            unsigned m0 = ((const unsigned*)(H + (size_t)s0 * 128))[lane];
            unsigned m1 = ((const unsigned*)(H + (size_t)s1 * 128))[lane];
            unsigned m2 = ((const unsigned*)(H + (size_t)s2 * 128))[lane];
            unsigned m3 = ((const unsigned*)(H + (size_t)s3 * 128))[lane];
            unsigned m4 = ((const unsigned*)(H + (size_t)s4 * 128))[lane];
            unsigned m5 = ((const unsigned*)(H + (size_t)s5 * 128))[lane];
            unsigned m6 = ((const unsigned*)(H + (size_t)s6 * 128))[lane];
            unsigned m7 = ((const unsigned*)(H + (size_t)s7 * 128))[lane];
            float2 f0 = h2f2(m0), f1 = h2f2(m1), f2 = h2f2(m2), f3 = h2f2(m3);
            float2 f4 = h2f2(m4), f5 = h2f2(m5), f6 = h2f2(m6), f7 = h2f2(m7);
            ax += ((f0.x + f1.x) + (f2.x + f3.x)) + ((f4.x + f5.x) + (f6.x + f7.x));
            ay += ((f0.y + f1.y) + (f2.y + f3.y)) + ((f4.y + f5.y) + (f6.y + f7.y));
        }
        for (; e < e1; e++) {
            int s = __builtin_amdgcn_readfirstlane(edge_src[e]);
            float2 m = h2f2(((const unsigned*)(H + (size_t)s * 128))[lane]);
            ax += m.x;
            ay += m.y;
        }
        const float d = dis[v];
        const float2 b = ((const float2*)bias)[lane];
        float ox = fmaf(ax, d, b.x);
        float oy = fmaf(ay, d, b.y);
        if constexpr (RELU) {
            ox = fmaxf(ox, 0.f);
            oy = fmaxf(oy, 0.f);
        }
        if constexpr (OUT_HALF) {
            __half2 o = __float22half2_rn(make_float2(ox, oy));
            ((unsigned*)OUT)[(size_t)v * 64 + lane] = __builtin_bit_cast(unsigned, o);
        } else {
            float2 o; o.x = ox; o.y = oy;
            ((float2*)OUT)[(size_t)v * 64 + lane] = o;
        }
    } else {
        float a = h2f(H[(size_t)v * 64 + lane]);  // self-loop
        int e = e0;
        for (; e + 8 <= e1; e += 8) {
            int myidx = edge_src[e + (lane & 7)];
            int s0 = __builtin_amdgcn_readlane(myidx, 0);
            int s1 = __builtin_amdgcn_readlane(myidx, 1);
            int s2 = __builtin_amdgcn_readlane(myidx, 2);
            int s3 = __builtin_amdgcn_readlane(myidx, 3);
            int s4 = __builtin_amdgcn_readlane(myidx, 4);
            int s5 = __builtin_amdgcn_readlane(myidx, 5);
            int s6 = __builtin_amdgcn_readlane(myidx, 6);
            int s7 = __builtin_amdgcn_readlane(myidx, 7);
            float m0 = h2f(H[(size_t)s0 * 64 + lane]);
            float m1 = h2f(H[(size_t)s1 * 64 + lane]);
            float m2 = h2f(H[(size_t)s2 * 64 + lane]);
            float m3 = h2f(H[(size_t)s3 * 64 + lane]);
            float m4 = h2f(H[(size_t)s4 * 64 + lane]);
            float m5 = h2f(H[(size_t)s5 * 64 + lane]);
            float m6 = h2f(H[(size_t)s6 * 64 + lane]);
            float m7 = h2f(H[(size_t)s7 * 64 + lane]);
            a += ((m0 + m1) + (m2 + m3)) + ((m4 + m5) + (m6 + m7));
        }
        for (; e < e1; e++) {
            int s = __builtin_amdgcn_readfirstlane(edge_src[e]);
            a += h2f(H[(size_t)s * 64 + lane]);
        }
        float o = fmaf(a, dis[v], bias[lane]);
        if constexpr (RELU) o = fmaxf(o, 0.f);
        if constexpr (OUT_HALF) {
            ((unsigned short*)OUT)[(size_t)v * 64 + lane] = f2h_bits(o);
        } else {
            ((float*)OUT)[(size_t)v * 64 + lane] = o;
        }
    }
}

// ---------------------------------------------------------------------------

extern "C" void kernel_launch(void* const* d_in, const int* in_sizes, int n_in,
                              void* d_out, int out_size, void* d_ws, size_t ws_size,
                              hipStream_t stream) {
    const float* x   = (const float*)d_in[0];
    const int* eidx  = (const int*)d_in[1];
    const float* W1  = (const float*)d_in[2];
    const float* b1  = (const float*)d_in[3];
    const float* W2  = (const float*)d_in[4];
    const float* b2  = (const float*)d_in[5];
    float* out = (float*)d_out;

    const int* erow = eidx;          // sources
    const int* ecol = eidx + EDGES;  // targets

    // workspace carve-up (256B aligned)
    char* w = (char*)d_ws;
    size_t off = 0;
    auto alloc = [&](size_t bytes) -> void* {
        void* p = w + off;
        off += (bytes + 255) & ~(size_t)255;
        return p;
    };
    int*   deg_cnt = (int*)alloc((size_t)NODES * 4);
    float* dis     = (float*)alloc((size_t)NODES * 4);
    int*   cursor  = (int*)alloc((size_t)NODES * 4);
    int*   rowst   = (int*)alloc((size_t)(NODES + 1) * 4);
    int*   esrc    = (int*)alloc((size_t)EDGES * 4);
    int*   bsum    = (int*)alloc(128 * 4);
    unsigned short* wh1 = (unsigned short*)alloc(2048 * 8 * 2);
    unsigned short* wl1 = (unsigned short*)alloc(2048 * 8 * 2);
    unsigned short* wh2 = (unsigned short*)alloc(1024 * 8 * 2);
    unsigned short* wl2 = (unsigned short*)alloc(1024 * 8 * 2);
    unsigned short* bufA = (unsigned short*)alloc((size_t)NODES * 128 * 2);  // h1' / h2' (fp16)
    unsigned short* bufB = (unsigned short*)alloc((size_t)NODES * 128 * 2);  // relu(out1) (fp16)

    hipMemsetAsync(deg_cnt, 0, (size_t)NODES * 4, stream);
    hipMemsetAsync(cursor, 0, (size_t)NODES * 4, stream);

    const int NB = (NODES + 1023) / 1024;  // 98

    count_kernel<<<(EDGES + 255) / 256, 256, 0, stream>>>(ecol, deg_cnt);
    dis_kernel<<<(NODES + 255) / 256, 256, 0, stream>>>(deg_cnt, dis);
    scan_reduce<<<NB, 1024, 0, stream>>>(deg_cnt, bsum);
    scan_sums<<<1, 128, 0, stream>>>(bsum, NB);
    scan_write<<<NB, 1024, 0, stream>>>(deg_cnt, bsum, rowst);
    fill_kernel<<<(EDGES + 255) / 256, 256, 0, stream>>>(erow, ecol, rowst, cursor, esrc);

    w_prep<128><<<8, 256, 0, stream>>>(W1, wh1, wl1);
    w_prep<64><<<4, 256, 0, stream>>>(W2, wh2, wl2);

    const int GB = (NODES + 127) / 128;  // 782

    // layer 1: h1' = (x @ W1)*dis (fp16) ; out1 = relu(dis*(agg+self)+b1) (fp16)
    gemm_mfma<128, false><<<GB, 512, 0, stream>>>(x, wh1, wl1, dis, bufA);
    agg_kernel<128, true, true><<<(NODES + 3) / 4, 256, 0, stream>>>(bufA, rowst, esrc, dis, b1, bufB);

    // layer 2: h2' = (out1 @ W2)*dis (fp16) ; out = dis*(agg+self)+b2 (f32)
    gemm_mfma<64, true><<<GB, 512, 0, stream>>>(bufB, wh2, wl2, dis, bufA);
    agg_kernel<64, false, false><<<(NODES + 3) / 4, 256, 0, stream>>>(bufA, rowst, esrc, dis, b2, out);
}

// Round 4
// 234.904 us; speedup vs baseline: 2.3800x; 1.5339x over previous
//
#include <hip/hip_runtime.h>
#include <hip/hip_fp16.h>

#define NODES 100000
#define EDGES 1600000

#define BSHIFT 9
#define BNODES 512                                   // nodes per bucket
#define NBUCK ((NODES + BNODES - 1) / BNODES)        // 196
#define BCAP 10240                                   // max edges per bucket (avg 8163)

typedef __attribute__((ext_vector_type(8))) short short8;
typedef __attribute__((ext_vector_type(4))) float f32x4;

// ---------------------------------------------------------------------------
// bf16 / fp16 helpers
// ---------------------------------------------------------------------------
__device__ inline unsigned short f2bf(float f) {
    unsigned u = __builtin_bit_cast(unsigned, f);
    u = u + 0x7fff + ((u >> 16) & 1);
    return (unsigned short)(u >> 16);
}
__device__ inline float bf2f(unsigned short h) {
    unsigned u = ((unsigned)h) << 16;
    return __builtin_bit_cast(float, u);
}
__device__ inline unsigned short f2h_bits(float f) {
    __half h = __float2half_rn(f);
    return __builtin_bit_cast(unsigned short, h);
}
__device__ inline float h2f(unsigned short bits) {
    return __half2float(__builtin_bit_cast(__half, bits));
}
__device__ inline float2 h2f2(unsigned int bits) {
    __half2 h = __builtin_bit_cast(__half2, bits);
    return __half22float2(h);
}

// ---------------------------------------------------------------------------
// CSR build, bucketed (dense writes):
//   A: multisplit edges into 196 node-range buckets (LDS hist + chunk reserve)
//   scan: 196 bucket sizes -> esrc bases
//   B: per-bucket counting sort in LDS; coalesced row_start/dis; dense esrc
// ---------------------------------------------------------------------------

__global__ __launch_bounds__(1024) void bucket_scatter(const int* __restrict__ row,
                                                       const int* __restrict__ col,
                                                       int* __restrict__ gcur,
                                                       int2* __restrict__ temp) {
    __shared__ int hist[NBUCK];
    __shared__ int base[NBUCK];
    const int tid = threadIdx.x;
    for (int i = tid; i < NBUCK; i += 1024) hist[i] = 0;
    __syncthreads();

    const int e = blockIdx.x * 1024 + tid;
    const bool valid = e < EDGES;
    int b = 0, rank = 0, src = 0, c = 0;
    if (valid) {
        c = col[e];
        src = row[e];
        b = c >> BSHIFT;
        rank = atomicAdd(&hist[b], 1);
    }
    __syncthreads();
    for (int i = tid; i < NBUCK; i += 1024) {
        int h = hist[i];
        base[i] = h ? atomicAdd(&gcur[i], h) : 0;
    }
    __syncthreads();
    if (valid) {
        int pos = base[b] + rank;
        int2 v;
        v.x = src;
        v.y = c & (BNODES - 1);
        temp[(size_t)b * BCAP + pos] = v;
    }
}

__global__ __launch_bounds__(256) void bucket_scan(const int* __restrict__ gcur,
                                                   int* __restrict__ bbase,
                                                   int* __restrict__ row_start) {
    __shared__ int s[256];
    const int t = threadIdx.x;
    int v = (t < NBUCK) ? gcur[t] : 0;
    s[t] = v;
    __syncthreads();
    for (int d = 1; d < 256; d <<= 1) {
        int x = (t >= d) ? s[t - d] : 0;
        __syncthreads();
        s[t] += x;
        __syncthreads();
    }
    if (t < NBUCK) bbase[t] = s[t] - v;  // exclusive
    if (t == 0) row_start[NODES] = EDGES;
}

__global__ __launch_bounds__(1024) void bucket_build(const int2* __restrict__ temp,
                                                     const int* __restrict__ gcur,
                                                     const int* __restrict__ bbase,
                                                     int* __restrict__ row_start,
                                                     float* __restrict__ dis,
                                                     int* __restrict__ esrc) {
    __shared__ int cnt[BNODES];
    __shared__ int offs[BNODES];
    __shared__ int cur[BNODES];
    const int b = blockIdx.x;
    const int tid = threadIdx.x;
    const int size = gcur[b];
    const int gbase = bbase[b];

    if (tid < BNODES) cnt[tid] = 0;
    __syncthreads();

    for (int i = tid; i < size; i += 1024) {
        int2 v = temp[(size_t)b * BCAP + i];
        atomicAdd(&cnt[v.y], 1);
    }
    __syncthreads();

    if (tid < BNODES) offs[tid] = cnt[tid];
    __syncthreads();
    for (int d = 1; d < BNODES; d <<= 1) {
        int x = 0;
        if (tid < BNODES && tid >= d) x = offs[tid - d];
        __syncthreads();
        if (tid < BNODES) offs[tid] += x;
        __syncthreads();
    }
    if (tid < BNODES) {
        int excl = offs[tid] - cnt[tid];
        cur[tid] = excl;
        int v = b * BNODES + tid;
        if (v < NODES) {
            row_start[v] = gbase + excl;
            dis[v] = rsqrtf((float)(cnt[tid] + 1));  // +1 self-loop
        }
    }
    __syncthreads();

    for (int i = tid; i < size; i += 1024) {
        int2 v = temp[(size_t)b * BCAP + i];
        int pos = gbase + atomicAdd(&cur[v.y], 1);
        esrc[pos] = v.x;
    }
}

// ---------------------------------------------------------------------------
// W prep: split f32 W[K=128][NCOL] into hi/lo bf16, fragment-major layout:
//   k = kt*32 + (lane>>4)*8 + i,  c = ct*16 + (lane&15)
// ---------------------------------------------------------------------------

template <int NCOL>
__global__ __launch_bounds__(256) void w_prep(const float* __restrict__ W,
                                              unsigned short* __restrict__ wh,
                                              unsigned short* __restrict__ wl) {
    constexpr int NCT = NCOL / 16;
    constexpr int FRAGS = 4 * NCT * 64;
    int idx = blockIdx.x * 256 + threadIdx.x;
    if (idx >= FRAGS) return;
    int lane = idx & 63;
    int rem = idx >> 6;
    int ct = rem % NCT;
    int kt = rem / NCT;
    int kbase = kt * 32 + ((lane >> 4) * 8);
    int c = ct * 16 + (lane & 15);
#pragma unroll
    for (int i = 0; i < 8; i++) {
        float v = W[(size_t)(kbase + i) * NCOL + c];
        unsigned short hi = f2bf(v);
        unsigned short lo = f2bf(v - bf2f(hi));
        wh[(size_t)idx * 8 + i] = hi;
        wl[(size_t)idx * 8 + i] = lo;
    }
}

// ---------------------------------------------------------------------------
// GEMM via MFMA 16x16x32 bf16, split-precision (xh@Wh + xl@Wh + xh@Wl):
//   H[r][:] = (X[r][:] @ W) * dis[r]
// IN_HALF: X is fp16 (exact bf16 hi/lo split). Output H is fp16.
// ---------------------------------------------------------------------------

template <int NCOL, bool IN_HALF>
__global__ __launch_bounds__(512) void gemm_mfma(const void* __restrict__ Xv,
                                                 const unsigned short* __restrict__ wh,
                                                 const unsigned short* __restrict__ wl,
                                                 const float* __restrict__ dis,
                                                 unsigned short* __restrict__ H) {
    constexpr int NCT = NCOL / 16;
    constexpr int FRAGS = 4 * NCT * 64;  // 2048 (NCOL=128) or 1024 (NCOL=64)
    __shared__ unsigned short s_wh[FRAGS * 8];
    __shared__ unsigned short s_wl[FRAGS * 8];

    const int tid = threadIdx.x;
    const int wave = tid >> 6;
    const int lane = tid & 63;

    const int row0 = blockIdx.x * 128 + wave * 16 + (lane & 15);
    const bool active = (blockIdx.x * 128 + wave * 16) < NODES;  // wave-uniform

    // prefetch A: per ktile, lane reads 8 contiguous elements of its row
    float xs[4][8];
    if (active) {
        if constexpr (IN_HALF) {
            const unsigned short* xrow = (const unsigned short*)Xv + (size_t)row0 * 128 + ((lane >> 4) * 8);
#pragma unroll
            for (int kt = 0; kt < 4; kt++) {
                short8 raw = *(const short8*)(xrow + kt * 32);
#pragma unroll
                for (int i = 0; i < 8; i++) xs[kt][i] = h2f((unsigned short)raw[i]);
            }
        } else {
            const float* xrow = (const float*)Xv + (size_t)row0 * 128 + ((lane >> 4) * 8);
#pragma unroll
            for (int kt = 0; kt < 4; kt++) {
                float4 a = *(const float4*)(xrow + kt * 32);
                float4 b = *(const float4*)(xrow + kt * 32 + 4);
                xs[kt][0] = a.x; xs[kt][1] = a.y; xs[kt][2] = a.z; xs[kt][3] = a.w;
                xs[kt][4] = b.x; xs[kt][5] = b.y; xs[kt][6] = b.z; xs[kt][7] = b.w;
            }
        }
    }

    // stage packed W into LDS (linear, 16B per lane per round)
    constexpr int ROUNDS = (FRAGS * 16) / (512 * 16);  // 4 or 2
#pragma unroll
    for (int j = 0; j < ROUNDS; j++) {
        __builtin_amdgcn_global_load_lds((const unsigned int*)((const char*)wh + ((size_t)tid + j * 512) * 16),
                                         (unsigned int*)(s_wh + ((size_t)tid + j * 512) * 8), 16, 0, 0);
        __builtin_amdgcn_global_load_lds((const unsigned int*)((const char*)wl + ((size_t)tid + j * 512) * 16),
                                         (unsigned int*)(s_wl + ((size_t)tid + j * 512) * 8), 16, 0, 0);
    }
    __syncthreads();

    if (!active) return;

    // convert A to bf16 hi/lo fragments
    short8 ah[4], al[4];
#pragma unroll
    for (int kt = 0; kt < 4; kt++) {
#pragma unroll
        for (int i = 0; i < 8; i++) {
            unsigned short hi = f2bf(xs[kt][i]);
            unsigned short lo = f2bf(xs[kt][i] - bf2f(hi));
            ah[kt][i] = (short)hi;
            al[kt][i] = (short)lo;
        }
    }

    f32x4 acc[NCT];
#pragma unroll
    for (int ct = 0; ct < NCT; ct++) acc[ct] = (f32x4){0.f, 0.f, 0.f, 0.f};

#pragma unroll
    for (int kt = 0; kt < 4; kt++) {
#pragma unroll
        for (int ct = 0; ct < NCT; ct++) {
            const int fo = ((kt * NCT + ct) * 64 + lane) * 8;
            short8 bh = *(const short8*)&s_wh[fo];
            short8 bl = *(const short8*)&s_wl[fo];
            acc[ct] = __builtin_amdgcn_mfma_f32_16x16x32_bf16(ah[kt], bh, acc[ct], 0, 0, 0);
            acc[ct] = __builtin_amdgcn_mfma_f32_16x16x32_bf16(al[kt], bh, acc[ct], 0, 0, 0);
            acc[ct] = __builtin_amdgcn_mfma_f32_16x16x32_bf16(ah[kt], bl, acc[ct], 0, 0, 0);
        }
    }

    // D layout: col = lane&15, row = (lane>>4)*4 + reg
    const int rbase = blockIdx.x * 128 + wave * 16 + ((lane >> 4) * 4);
    float d[4];
#pragma unroll
    for (int r = 0; r < 4; r++) d[r] = dis[rbase + r];
#pragma unroll
    for (int ct = 0; ct < NCT; ct++) {
#pragma unroll
        for (int r = 0; r < 4; r++) {
            H[(size_t)(rbase + r) * NCOL + ct * 16 + (lane & 15)] = f2h_bits(acc[ct][r] * d[r]);
        }
    }
}

// ---------------------------------------------------------------------------
// Aggregation (fp16 H): OUT[v] = act( dis[v]*(sum_{CSR(v)} H[src] + H[v]) + b )
// One wave per node, 8-deep edge unroll, edge indices via readlane (SGPR base).
// ---------------------------------------------------------------------------

template <int C, bool RELU, bool OUT_HALF>
__global__ __launch_bounds__(256) void agg_kernel(const unsigned short* __restrict__ H,
                                                  const int* __restrict__ row_start,
                                                  const int* __restrict__ edge_src,
                                                  const float* __restrict__ dis,
                                                  const float* __restrict__ bias,
                                                  void* __restrict__ OUT) {
    const int wave = threadIdx.x >> 6;
    const int lane = threadIdx.x & 63;
    const int v = blockIdx.x * 4 + wave;
    if (v >= NODES) return;

    const int e0 = row_start[v];
    const int e1 = row_start[v + 1];

    if constexpr (C == 128) {
        float ax, ay;
        {
            unsigned self = ((const unsigned*)(H + (size_t)v * 128))[lane];
            float2 s2 = h2f2(self);
            ax = s2.x; ay = s2.y;
        }
        int e = e0;
        for (; e + 8 <= e1; e += 8) {
            int myidx = edge_src[e + (lane & 7)];
            int s0 = __builtin_amdgcn_readlane(myidx, 0);
            int s1 = __builtin_amdgcn_readlane(myidx, 1);
            int s2 = __builtin_amdgcn_readlane(myidx, 2);
            int s3 = __builtin_amdgcn_readlane(myidx, 3);
            int s4 = __builtin_amdgcn_readlane(myidx, 4);
            int s5 = __builtin_amdgcn_readlane(myidx, 5);
            int s6 = __builtin_amdgcn_readlane(myidx, 6);
            int s7 = __builtin_amdgcn_readlane(myidx, 7);
            unsigned m0 = ((const unsigned*)(H + (size_t)s0 * 128))[lane];
            unsigned m1 = ((const unsigned*)(H + (size_t)s1 * 128))[lane];
            unsigned m2 = ((const unsigned*)(H + (size_t)s2 * 128))[lane];
            unsigned m3 = ((const unsigned*)(H + (size_t)s3 * 128))[lane];
            unsigned m4 = ((const unsigned*)(H + (size_t)s4 * 128))[lane];
            unsigned m5 = ((const unsigned*)(H + (size_t)s5 * 128))[lane];
            unsigned m6 = ((const unsigned*)(H + (size_t)s6 * 128))[lane];
            unsigned m7 = ((const unsigned*)(H + (size_t)s7 * 128))[lane];
            float2 f0 = h2f2(m0), f1 = h2f2(m1), f2 = h2f2(m2), f3 = h2f2(m3);
            float2 f4 = h2f2(m4), f5 = h2f2(m5), f6 = h2f2(m6), f7 = h2f2(m7);
            ax += ((f0.x + f1.x) + (f2.x + f3.x)) + ((f4.x + f5.x) + (f6.x + f7.x));
            ay += ((f0.y + f1.y) + (f2.y + f3.y)) + ((f4.y + f5.y) + (f6.y + f7.y));
        }
        for (; e < e1; e++) {
            int s = __builtin_amdgcn_readfirstlane(edge_src[e]);
            float2 m = h2f2(((const unsigned*)(H + (size_t)s * 128))[lane]);
            ax += m.x;
            ay += m.y;
        }
        const float d = dis[v];
        const float2 b = ((const float2*)bias)[lane];
        float ox = fmaf(ax, d, b.x);
        float oy = fmaf(ay, d, b.y);
        if constexpr (RELU) {
            ox = fmaxf(ox, 0.f);
            oy = fmaxf(oy, 0.f);
        }
        if constexpr (OUT_HALF) {
            __half2 o = __float22half2_rn(make_float2(ox, oy));
            ((unsigned*)OUT)[(size_t)v * 64 + lane] = __builtin_bit_cast(unsigned, o);
        } else {
            float2 o; o.x = ox; o.y = oy;
            ((float2*)OUT)[(size_t)v * 64 + lane] = o;
        }
    } else {
        float a = h2f(H[(size_t)v * 64 + lane]);  // self-loop
        int e = e0;
        for (; e + 8 <= e1; e += 8) {
            int myidx = edge_src[e + (lane & 7)];
            int s0 = __builtin_amdgcn_readlane(myidx, 0);
            int s1 = __builtin_amdgcn_readlane(myidx, 1);
            int s2 = __builtin_amdgcn_readlane(myidx, 2);
            int s3 = __builtin_amdgcn_readlane(myidx, 3);
            int s4 = __builtin_amdgcn_readlane(myidx, 4);
            int s5 = __builtin_amdgcn_readlane(myidx, 5);
            int s6 = __builtin_amdgcn_readlane(myidx, 6);
            int s7 = __builtin_amdgcn_readlane(myidx, 7);
            float m0 = h2f(H[(size_t)s0 * 64 + lane]);
            float m1 = h2f(H[(size_t)s1 * 64 + lane]);
            float m2 = h2f(H[(size_t)s2 * 64 + lane]);
            float m3 = h2f(H[(size_t)s3 * 64 + lane]);
            float m4 = h2f(H[(size_t)s4 * 64 + lane]);
            float m5 = h2f(H[(size_t)s5 * 64 + lane]);
            float m6 = h2f(H[(size_t)s6 * 64 + lane]);
            float m7 = h2f(H[(size_t)s7 * 64 + lane]);
            a += ((m0 + m1) + (m2 + m3)) + ((m4 + m5) + (m6 + m7));
        }
        for (; e < e1; e++) {
            int s = __builtin_amdgcn_readfirstlane(edge_src[e]);
            a += h2f(H[(size_t)s * 64 + lane]);
        }
        float o = fmaf(a, dis[v], bias[lane]);
        if constexpr (RELU) o = fmaxf(o, 0.f);
        if constexpr (OUT_HALF) {
            ((unsigned short*)OUT)[(size_t)v * 64 + lane] = f2h_bits(o);
        } else {
            ((float*)OUT)[(size_t)v * 64 + lane] = o;
        }
    }
}

// ---------------------------------------------------------------------------

extern "C" void kernel_launch(void* const* d_in, const int* in_sizes, int n_in,
                              void* d_out, int out_size, void* d_ws, size_t ws_size,
                              hipStream_t stream) {
    const float* x   = (const float*)d_in[0];
    const int* eidx  = (const int*)d_in[1];
    const float* W1  = (const float*)d_in[2];
    const float* b1  = (const float*)d_in[3];
    const float* W2  = (const float*)d_in[4];
    const float* b2  = (const float*)d_in[5];
    float* out = (float*)d_out;

    const int* erow = eidx;          // sources
    const int* ecol = eidx + EDGES;  // targets

    // workspace carve-up (256B aligned)
    char* w = (char*)d_ws;
    size_t off = 0;
    auto alloc = [&](size_t bytes) -> void* {
        void* p = w + off;
        off += (bytes + 255) & ~(size_t)255;
        return p;
    };
    float* dis     = (float*)alloc((size_t)NODES * 4);
    int*   rowst   = (int*)alloc((size_t)(NODES + 1) * 4);
    int*   esrc    = (int*)alloc((size_t)EDGES * 4);
    int*   gcur    = (int*)alloc(NBUCK * 4);
    int*   bbase   = (int*)alloc(NBUCK * 4);
    int2*  temp    = (int2*)alloc((size_t)NBUCK * BCAP * 8);
    unsigned short* wh1 = (unsigned short*)alloc(2048 * 8 * 2);
    unsigned short* wl1 = (unsigned short*)alloc(2048 * 8 * 2);
    unsigned short* wh2 = (unsigned short*)alloc(1024 * 8 * 2);
    unsigned short* wl2 = (unsigned short*)alloc(1024 * 8 * 2);
    unsigned short* bufA = (unsigned short*)alloc((size_t)NODES * 128 * 2);  // h1' / h2' (fp16)
    unsigned short* bufB = (unsigned short*)alloc((size_t)NODES * 128 * 2);  // relu(out1) (fp16)

    hipMemsetAsync(gcur, 0, NBUCK * 4, stream);

    // CSR build (bucketed, dense writes)
    bucket_scatter<<<(EDGES + 1023) / 1024, 1024, 0, stream>>>(erow, ecol, gcur, temp);
    bucket_scan<<<1, 256, 0, stream>>>(gcur, bbase, rowst);
    bucket_build<<<NBUCK, 1024, 0, stream>>>(temp, gcur, bbase, rowst, dis, esrc);

    w_prep<128><<<8, 256, 0, stream>>>(W1, wh1, wl1);
    w_prep<64><<<4, 256, 0, stream>>>(W2, wh2, wl2);

    const int GB = (NODES + 127) / 128;  // 782

    // layer 1: h1' = (x @ W1)*dis (fp16) ; out1 = relu(dis*(agg+self)+b1) (fp16)
    gemm_mfma<128, false><<<GB, 512, 0, stream>>>(x, wh1, wl1, dis, bufA);
    agg_kernel<128, true, true><<<(NODES + 3) / 4, 256, 0, stream>>>(bufA, rowst, esrc, dis, b1, bufB);

    // layer 2: h2' = (out1 @ W2)*dis (fp16) ; out = dis*(agg+self)+b2 (f32)
    gemm_mfma<64, true><<<GB, 512, 0, stream>>>(bufB, wh2, wl2, dis, bufA);
    agg_kernel<64, false, false><<<(NODES + 3) / 4, 256, 0, stream>>>(bufA, rowst, esrc, dis, b2, out);
}

// Round 5
// 209.402 us; speedup vs baseline: 2.6699x; 1.1218x over previous
//
#include <hip/hip_runtime.h>
#include <hip/hip_fp16.h>

#define NODES 100000
#define EDGES 1600000

#define BSHIFT 9
#define BNODES 512                                   // nodes per bucket
#define NBUCK ((NODES + BNODES - 1) / BNODES)        // 196
#define BCAP 10240                                   // max edges per bucket (avg 8163)

#define AGG_BLOCKS 2048
#define AGG_WAVES (AGG_BLOCKS * 4)

typedef __attribute__((ext_vector_type(8))) short short8;
typedef __attribute__((ext_vector_type(4))) float f32x4;

// ---------------------------------------------------------------------------
// bf16 / fp16 helpers
// ---------------------------------------------------------------------------
__device__ inline unsigned short f2bf(float f) {
    unsigned u = __builtin_bit_cast(unsigned, f);
    u = u + 0x7fff + ((u >> 16) & 1);
    return (unsigned short)(u >> 16);
}
__device__ inline float bf2f(unsigned short h) {
    unsigned u = ((unsigned)h) << 16;
    return __builtin_bit_cast(float, u);
}
__device__ inline unsigned short f2h_bits(float f) {
    __half h = __float2half_rn(f);
    return __builtin_bit_cast(unsigned short, h);
}
__device__ inline float h2f(unsigned short bits) {
    return __half2float(__builtin_bit_cast(__half, bits));
}
__device__ inline float2 h2f2(unsigned int bits) {
    __half2 h = __builtin_bit_cast(__half2, bits);
    return __half22float2(h);
}

// ---------------------------------------------------------------------------
// CSR build, bucketed (dense writes)
// ---------------------------------------------------------------------------

__global__ __launch_bounds__(1024) void bucket_scatter(const int* __restrict__ row,
                                                       const int* __restrict__ col,
                                                       int* __restrict__ gcur,
                                                       int2* __restrict__ temp) {
    __shared__ int hist[NBUCK];
    __shared__ int base[NBUCK];
    const int tid = threadIdx.x;
    for (int i = tid; i < NBUCK; i += 1024) hist[i] = 0;
    __syncthreads();

    const int e = blockIdx.x * 1024 + tid;
    const bool valid = e < EDGES;
    int b = 0, rank = 0, src = 0, c = 0;
    if (valid) {
        c = col[e];
        src = row[e];
        b = c >> BSHIFT;
        rank = atomicAdd(&hist[b], 1);
    }
    __syncthreads();
    for (int i = tid; i < NBUCK; i += 1024) {
        int h = hist[i];
        base[i] = h ? atomicAdd(&gcur[i], h) : 0;
    }
    __syncthreads();
    if (valid) {
        int pos = base[b] + rank;
        int2 v;
        v.x = src;
        v.y = c & (BNODES - 1);
        temp[(size_t)b * BCAP + pos] = v;
    }
}

__global__ __launch_bounds__(256) void bucket_scan(const int* __restrict__ gcur,
                                                   int* __restrict__ bbase,
                                                   int* __restrict__ row_start) {
    __shared__ int s[256];
    const int t = threadIdx.x;
    int v = (t < NBUCK) ? gcur[t] : 0;
    s[t] = v;
    __syncthreads();
    for (int d = 1; d < 256; d <<= 1) {
        int x = (t >= d) ? s[t - d] : 0;
        __syncthreads();
        s[t] += x;
        __syncthreads();
    }
    if (t < NBUCK) bbase[t] = s[t] - v;  // exclusive
    if (t == 0) row_start[NODES] = EDGES;
}

__global__ __launch_bounds__(1024) void bucket_build(const int2* __restrict__ temp,
                                                     const int* __restrict__ gcur,
                                                     const int* __restrict__ bbase,
                                                     int* __restrict__ row_start,
                                                     float* __restrict__ dis,
                                                     int* __restrict__ esrc) {
    __shared__ int cnt[BNODES];
    __shared__ int offs[BNODES];
    __shared__ int cur[BNODES];
    const int b = blockIdx.x;
    const int tid = threadIdx.x;
    const int size = gcur[b];
    const int gbase = bbase[b];

    if (tid < BNODES) cnt[tid] = 0;
    __syncthreads();

    for (int i = tid; i < size; i += 1024) {
        int2 v = temp[(size_t)b * BCAP + i];
        atomicAdd(&cnt[v.y], 1);
    }
    __syncthreads();

    if (tid < BNODES) offs[tid] = cnt[tid];
    __syncthreads();
    for (int d = 1; d < BNODES; d <<= 1) {
        int x = 0;
        if (tid < BNODES && tid >= d) x = offs[tid - d];
        __syncthreads();
        if (tid < BNODES) offs[tid] += x;
        __syncthreads();
    }
    if (tid < BNODES) {
        int excl = offs[tid] - cnt[tid];
        cur[tid] = excl;
        int v = b * BNODES + tid;
        if (v < NODES) {
            row_start[v] = gbase + excl;
            dis[v] = rsqrtf((float)(cnt[tid] + 1));  // +1 self-loop
        }
    }
    __syncthreads();

    for (int i = tid; i < size; i += 1024) {
        int2 v = temp[(size_t)b * BCAP + i];
        int pos = gbase + atomicAdd(&cur[v.y], 1);
        esrc[pos] = v.x;
    }
}

// ---------------------------------------------------------------------------
// W prep: split f32 W[K=128][NCOL] into hi/lo bf16, fragment-major layout
// ---------------------------------------------------------------------------

template <int NCOL>
__global__ __launch_bounds__(256) void w_prep(const float* __restrict__ W,
                                              unsigned short* __restrict__ wh,
                                              unsigned short* __restrict__ wl) {
    constexpr int NCT = NCOL / 16;
    constexpr int FRAGS = 4 * NCT * 64;
    int idx = blockIdx.x * 256 + threadIdx.x;
    if (idx >= FRAGS) return;
    int lane = idx & 63;
    int rem = idx >> 6;
    int ct = rem % NCT;
    int kt = rem / NCT;
    int kbase = kt * 32 + ((lane >> 4) * 8);
    int c = ct * 16 + (lane & 15);
#pragma unroll
    for (int i = 0; i < 8; i++) {
        float v = W[(size_t)(kbase + i) * NCOL + c];
        unsigned short hi = f2bf(v);
        unsigned short lo = f2bf(v - bf2f(hi));
        wh[(size_t)idx * 8 + i] = hi;
        wl[(size_t)idx * 8 + i] = lo;
    }
}

// ---------------------------------------------------------------------------
// GEMM via MFMA 16x16x32 bf16, split-precision (xh@Wh + xl@Wh + xh@Wl)
// ---------------------------------------------------------------------------

template <int NCOL, bool IN_HALF>
__global__ __launch_bounds__(512) void gemm_mfma(const void* __restrict__ Xv,
                                                 const unsigned short* __restrict__ wh,
                                                 const unsigned short* __restrict__ wl,
                                                 const float* __restrict__ dis,
                                                 unsigned short* __restrict__ H) {
    constexpr int NCT = NCOL / 16;
    constexpr int FRAGS = 4 * NCT * 64;  // 2048 (NCOL=128) or 1024 (NCOL=64)
    __shared__ unsigned short s_wh[FRAGS * 8];
    __shared__ unsigned short s_wl[FRAGS * 8];

    const int tid = threadIdx.x;
    const int wave = tid >> 6;
    const int lane = tid & 63;

    const int row0 = blockIdx.x * 128 + wave * 16 + (lane & 15);
    const bool active = (blockIdx.x * 128 + wave * 16) < NODES;  // wave-uniform

    // prefetch A: per ktile, lane reads 8 contiguous elements of its row
    float xs[4][8];
    if (active) {
        if constexpr (IN_HALF) {
            const unsigned short* xrow = (const unsigned short*)Xv + (size_t)row0 * 128 + ((lane >> 4) * 8);
#pragma unroll
            for (int kt = 0; kt < 4; kt++) {
                short8 raw = *(const short8*)(xrow + kt * 32);
#pragma unroll
                for (int i = 0; i < 8; i++) xs[kt][i] = h2f((unsigned short)raw[i]);
            }
        } else {
            const float* xrow = (const float*)Xv + (size_t)row0 * 128 + ((lane >> 4) * 8);
#pragma unroll
            for (int kt = 0; kt < 4; kt++) {
                float4 a = *(const float4*)(xrow + kt * 32);
                float4 b = *(const float4*)(xrow + kt * 32 + 4);
                xs[kt][0] = a.x; xs[kt][1] = a.y; xs[kt][2] = a.z; xs[kt][3] = a.w;
                xs[kt][4] = b.x; xs[kt][5] = b.y; xs[kt][6] = b.z; xs[kt][7] = b.w;
            }
        }
    }

    // stage packed W into LDS (linear, 16B per lane per round)
    constexpr int ROUNDS = (FRAGS * 16) / (512 * 16);  // 4 or 2
#pragma unroll
    for (int j = 0; j < ROUNDS; j++) {
        __builtin_amdgcn_global_load_lds((const unsigned int*)((const char*)wh + ((size_t)tid + j * 512) * 16),
                                         (unsigned int*)(s_wh + ((size_t)tid + j * 512) * 8), 16, 0, 0);
        __builtin_amdgcn_global_load_lds((const unsigned int*)((const char*)wl + ((size_t)tid + j * 512) * 16),
                                         (unsigned int*)(s_wl + ((size_t)tid + j * 512) * 8), 16, 0, 0);
    }
    __syncthreads();

    if (!active) return;

    // convert A to bf16 hi/lo fragments
    short8 ah[4], al[4];
#pragma unroll
    for (int kt = 0; kt < 4; kt++) {
#pragma unroll
        for (int i = 0; i < 8; i++) {
            unsigned short hi = f2bf(xs[kt][i]);
            unsigned short lo = f2bf(xs[kt][i] - bf2f(hi));
            ah[kt][i] = (short)hi;
            al[kt][i] = (short)lo;
        }
    }

    f32x4 acc[NCT];
#pragma unroll
    for (int ct = 0; ct < NCT; ct++) acc[ct] = (f32x4){0.f, 0.f, 0.f, 0.f};

#pragma unroll
    for (int kt = 0; kt < 4; kt++) {
#pragma unroll
        for (int ct = 0; ct < NCT; ct++) {
            const int fo = ((kt * NCT + ct) * 64 + lane) * 8;
            short8 bh = *(const short8*)&s_wh[fo];
            short8 bl = *(const short8*)&s_wl[fo];
            acc[ct] = __builtin_amdgcn_mfma_f32_16x16x32_bf16(ah[kt], bh, acc[ct], 0, 0, 0);
            acc[ct] = __builtin_amdgcn_mfma_f32_16x16x32_bf16(al[kt], bh, acc[ct], 0, 0, 0);
            acc[ct] = __builtin_amdgcn_mfma_f32_16x16x32_bf16(ah[kt], bl, acc[ct], 0, 0, 0);
        }
    }

    // D layout: col = lane&15, row = (lane>>4)*4 + reg
    const int rbase = blockIdx.x * 128 + wave * 16 + ((lane >> 4) * 4);
    float d[4];
#pragma unroll
    for (int r = 0; r < 4; r++) d[r] = dis[rbase + r];
#pragma unroll
    for (int ct = 0; ct < NCT; ct++) {
#pragma unroll
        for (int r = 0; r < 4; r++) {
            H[(size_t)(rbase + r) * NCOL + ct * 16 + (lane & 15)] = f2h_bits(acc[ct][r] * d[r]);
        }
    }
}

// ---------------------------------------------------------------------------
// Aggregation (fp16 H): OUT[v] = act( dis[v]*(sum_{CSR(v)} H[src] + H[v]) + b )
// One wave per node, grid-stride. 16-edge chunks, 2 edges per load instruction
// (lane<32 -> edge A, lane>=32 -> edge B), prefetched edge indices, final
// __shfl_xor(32) half-combine.
//   C=128: lane covers fp16 cols 4*(lane&31)..+3 (uint2/lane, 8B).
//   C=64 : lane covers fp16 cols 2*(lane&31)..+1 (uint/lane, 4B).
// ---------------------------------------------------------------------------

template <int C, bool RELU, bool OUT_HALF>
__global__ __launch_bounds__(256, 8) void agg_kernel(const unsigned short* __restrict__ H,
                                                     const int* __restrict__ row_start,
                                                     const int* __restrict__ edge_src,
                                                     const float* __restrict__ dis,
                                                     const float* __restrict__ bias,
                                                     void* __restrict__ OUT) {
    const int lane = threadIdx.x & 63;
    const int lane31 = lane & 31;
    const bool hiHalf = lane >= 32;
    const int wgid = blockIdx.x * 4 + (threadIdx.x >> 6);
    const unsigned* __restrict__ Hu = (const unsigned*)H;
    constexpr int RW = C / 2;  // row length in u32

    for (int v = wgid; v < NODES; v += AGG_WAVES) {
        const int e0 = row_start[v];
        const int e1 = row_start[v + 1];

        float a0x = 0.f, a0y = 0.f, a1x = 0.f, a1y = 0.f;

        int e = e0;
        int idxv = edge_src[min(e0 + (lane & 15), EDGES - 1)];

        for (; e + 16 <= e1; e += 16) {
            uint2 g2[8];
            unsigned g1[8];
#pragma unroll
            for (int k = 0; k < 8; k++) {
                int sA = __builtin_amdgcn_readlane(idxv, 2 * k);
                int sB = __builtin_amdgcn_readlane(idxv, 2 * k + 1);
                int s = hiHalf ? sB : sA;
                if constexpr (C == 128) {
                    g2[k] = *(const uint2*)(Hu + (size_t)s * RW + lane31 * 2);
                } else {
                    g1[k] = Hu[(size_t)s * RW + lane31];
                }
            }
            // prefetch next chunk's indices (issued after gathers -> accumulate
            // waits vmcnt(1); next readlane finds idxv already resident)
            idxv = edge_src[min(e + 16 + (lane & 15), EDGES - 1)];
#pragma unroll
            for (int k = 0; k < 8; k++) {
                if constexpr (C == 128) {
                    float2 fx = h2f2(g2[k].x), fy = h2f2(g2[k].y);
                    a0x += fx.x; a0y += fx.y; a1x += fy.x; a1y += fy.y;
                } else {
                    float2 f = h2f2(g1[k]);
                    a0x += f.x; a0y += f.y;
                }
            }
        }

        // remainder (indices already in idxv lanes 0..r-1)
        {
            const int r = e1 - e;
            int j = 0;
            for (; j + 2 <= r; j += 2) {
                int sA = __builtin_amdgcn_readlane(idxv, j);
                int sB = __builtin_amdgcn_readlane(idxv, j + 1);
                int s = hiHalf ? sB : sA;
                if constexpr (C == 128) {
                    uint2 g = *(const uint2*)(Hu + (size_t)s * RW + lane31 * 2);
                    float2 fx = h2f2(g.x), fy = h2f2(g.y);
                    a0x += fx.x; a0y += fx.y; a1x += fy.x; a1y += fy.y;
                } else {
                    float2 f = h2f2(Hu[(size_t)s * RW + lane31]);
                    a0x += f.x; a0y += f.y;
                }
            }
            if (j < r) {
                int s = __builtin_amdgcn_readlane(idxv, j);
                if constexpr (C == 128) {
                    uint2 g = *(const uint2*)(Hu + (size_t)s * RW + lane31 * 2);
                    if (!hiHalf) {
                        float2 fx = h2f2(g.x), fy = h2f2(g.y);
                        a0x += fx.x; a0y += fx.y; a1x += fy.x; a1y += fy.y;
                    }
                } else {
                    unsigned g = Hu[(size_t)s * RW + lane31];
                    if (!hiHalf) {
                        float2 f = h2f2(g);
                        a0x += f.x; a0y += f.y;
                    }
                }
            }
        }

        // combine half-wave partials (lane l and l^32 cover the same columns)
        a0x += __shfl_xor(a0x, 32);
        a0y += __shfl_xor(a0y, 32);
        if constexpr (C == 128) {
            a1x += __shfl_xor(a1x, 32);
            a1y += __shfl_xor(a1y, 32);
        }

        // self-loop (added once per duplicated copy — consistent across halves)
        if constexpr (C == 128) {
            uint2 g = *(const uint2*)(Hu + (size_t)v * RW + lane31 * 2);
            float2 fx = h2f2(g.x), fy = h2f2(g.y);
            a0x += fx.x; a0y += fx.y; a1x += fy.x; a1y += fy.y;
        } else {
            float2 f = h2f2(Hu[(size_t)v * RW + lane31]);
            a0x += f.x; a0y += f.y;
        }

        const float d = dis[v];
        if constexpr (C == 128) {
            const float4 b = ((const float4*)bias)[lane31];
            float o0 = fmaf(a0x, d, b.x);
            float o1 = fmaf(a0y, d, b.y);
            float o2 = fmaf(a1x, d, b.z);
            float o3 = fmaf(a1y, d, b.w);
            if constexpr (RELU) {
                o0 = fmaxf(o0, 0.f); o1 = fmaxf(o1, 0.f);
                o2 = fmaxf(o2, 0.f); o3 = fmaxf(o3, 0.f);
            }
            if (!hiHalf) {
                if constexpr (OUT_HALF) {
                    uint2 o;
                    o.x = __builtin_bit_cast(unsigned, __float22half2_rn(make_float2(o0, o1)));
                    o.y = __builtin_bit_cast(unsigned, __float22half2_rn(make_float2(o2, o3)));
                    ((uint2*)OUT)[(size_t)v * 32 + lane31] = o;
                } else {
                    float4 o; o.x = o0; o.y = o1; o.z = o2; o.w = o3;
                    ((float4*)OUT)[(size_t)v * 32 + lane31] = o;
                }
            }
        } else {
            const float2 b = ((const float2*)bias)[lane31];
            float o0 = fmaf(a0x, d, b.x);
            float o1 = fmaf(a0y, d, b.y);
            if constexpr (RELU) {
                o0 = fmaxf(o0, 0.f); o1 = fmaxf(o1, 0.f);
            }
            if (!hiHalf) {
                if constexpr (OUT_HALF) {
                    ((unsigned*)OUT)[(size_t)v * 32 + lane31] =
                        __builtin_bit_cast(unsigned, __float22half2_rn(make_float2(o0, o1)));
                } else {
                    float2 o; o.x = o0; o.y = o1;
                    ((float2*)OUT)[(size_t)v * 32 + lane31] = o;
                }
            }
        }
    }
}

// ---------------------------------------------------------------------------

extern "C" void kernel_launch(void* const* d_in, const int* in_sizes, int n_in,
                              void* d_out, int out_size, void* d_ws, size_t ws_size,
                              hipStream_t stream) {
    const float* x   = (const float*)d_in[0];
    const int* eidx  = (const int*)d_in[1];
    const float* W1  = (const float*)d_in[2];
    const float* b1  = (const float*)d_in[3];
    const float* W2  = (const float*)d_in[4];
    const float* b2  = (const float*)d_in[5];
    float* out = (float*)d_out;

    const int* erow = eidx;          // sources
    const int* ecol = eidx + EDGES;  // targets

    // workspace carve-up (256B aligned)
    char* w = (char*)d_ws;
    size_t off = 0;
    auto alloc = [&](size_t bytes) -> void* {
        void* p = w + off;
        off += (bytes + 255) & ~(size_t)255;
        return p;
    };
    float* dis     = (float*)alloc((size_t)NODES * 4);
    int*   rowst   = (int*)alloc((size_t)(NODES + 1) * 4);
    int*   esrc    = (int*)alloc((size_t)EDGES * 4);
    int*   gcur    = (int*)alloc(NBUCK * 4);
    int*   bbase   = (int*)alloc(NBUCK * 4);
    int2*  temp    = (int2*)alloc((size_t)NBUCK * BCAP * 8);
    unsigned short* wh1 = (unsigned short*)alloc(2048 * 8 * 2);
    unsigned short* wl1 = (unsigned short*)alloc(2048 * 8 * 2);
    unsigned short* wh2 = (unsigned short*)alloc(1024 * 8 * 2);
    unsigned short* wl2 = (unsigned short*)alloc(1024 * 8 * 2);
    unsigned short* bufA = (unsigned short*)alloc((size_t)NODES * 128 * 2);  // h1' / h2' (fp16)
    unsigned short* bufB = (unsigned short*)alloc((size_t)NODES * 128 * 2);  // relu(out1) (fp16)

    hipMemsetAsync(gcur, 0, NBUCK * 4, stream);

    // CSR build (bucketed, dense writes)
    bucket_scatter<<<(EDGES + 1023) / 1024, 1024, 0, stream>>>(erow, ecol, gcur, temp);
    bucket_scan<<<1, 256, 0, stream>>>(gcur, bbase, rowst);
    bucket_build<<<NBUCK, 1024, 0, stream>>>(temp, gcur, bbase, rowst, dis, esrc);

    w_prep<128><<<8, 256, 0, stream>>>(W1, wh1, wl1);
    w_prep<64><<<4, 256, 0, stream>>>(W2, wh2, wl2);

    const int GB = (NODES + 127) / 128;  // 782

    // layer 1: h1' = (x @ W1)*dis (fp16) ; out1 = relu(dis*(agg+self)+b1) (fp16)
    gemm_mfma<128, false><<<GB, 512, 0, stream>>>(x, wh1, wl1, dis, bufA);
    agg_kernel<128, true, true><<<AGG_BLOCKS, 256, 0, stream>>>(bufA, rowst, esrc, dis, b1, bufB);

    // layer 2: h2' = (out1 @ W2)*dis (fp16) ; out = dis*(agg+self)+b2 (f32)
    gemm_mfma<64, true><<<GB, 512, 0, stream>>>(bufB, wh2, wl2, dis, bufA);
    agg_kernel<64, false, false><<<AGG_BLOCKS, 256, 0, stream>>>(bufA, rowst, esrc, dis, b2, out);
}

// Round 6
// 195.230 us; speedup vs baseline: 2.8637x; 1.0726x over previous
//
#include <hip/hip_runtime.h>
#include <hip/hip_fp16.h>

#define NODES 100000
#define EDGES 1600000

#define BSHIFT 9
#define BNODES 512                                   // nodes per bucket
#define NBUCK ((NODES + BNODES - 1) / BNODES)        // 196
#define BCAP 10240                                   // max edges per bucket (avg 8163)

typedef __attribute__((ext_vector_type(8))) short short8;
typedef __attribute__((ext_vector_type(4))) float f32x4;

// ---------------------------------------------------------------------------
// bf16 / fp16 helpers
// ---------------------------------------------------------------------------
__device__ inline unsigned short f2bf(float f) {
    unsigned u = __builtin_bit_cast(unsigned, f);
    u = u + 0x7fff + ((u >> 16) & 1);
    return (unsigned short)(u >> 16);
}
__device__ inline float bf2f(unsigned short h) {
    unsigned u = ((unsigned)h) << 16;
    return __builtin_bit_cast(float, u);
}
__device__ inline unsigned short f2h_bits(float f) {
    __half h = __float2half_rn(f);
    return __builtin_bit_cast(unsigned short, h);
}
__device__ inline float h2f(unsigned short bits) {
    return __half2float(__builtin_bit_cast(__half, bits));
}
__device__ inline float2 h2f2(unsigned int bits) {
    __half2 h = __builtin_bit_cast(__half2, bits);
    return __half22float2(h);
}

// ---------------------------------------------------------------------------
// CSR build, bucketed (dense writes)
// ---------------------------------------------------------------------------

__global__ __launch_bounds__(1024) void bucket_scatter(const int* __restrict__ row,
                                                       const int* __restrict__ col,
                                                       int* __restrict__ gcur,
                                                       int2* __restrict__ temp) {
    __shared__ int hist[NBUCK];
    __shared__ int base[NBUCK];
    const int tid = threadIdx.x;
    for (int i = tid; i < NBUCK; i += 1024) hist[i] = 0;
    __syncthreads();

    const int e = blockIdx.x * 1024 + tid;
    const bool valid = e < EDGES;
    int b = 0, rank = 0, src = 0, c = 0;
    if (valid) {
        c = col[e];
        src = row[e];
        b = c >> BSHIFT;
        rank = atomicAdd(&hist[b], 1);
    }
    __syncthreads();
    for (int i = tid; i < NBUCK; i += 1024) {
        int h = hist[i];
        base[i] = h ? atomicAdd(&gcur[i], h) : 0;
    }
    __syncthreads();
    if (valid) {
        int pos = base[b] + rank;
        int2 v;
        v.x = src;
        v.y = c & (BNODES - 1);
        temp[(size_t)b * BCAP + pos] = v;
    }
}

__global__ __launch_bounds__(256) void bucket_scan(const int* __restrict__ gcur,
                                                   int* __restrict__ bbase,
                                                   int* __restrict__ row_start) {
    __shared__ int s[256];
    const int t = threadIdx.x;
    int v = (t < NBUCK) ? gcur[t] : 0;
    s[t] = v;
    __syncthreads();
    for (int d = 1; d < 256; d <<= 1) {
        int x = (t >= d) ? s[t - d] : 0;
        __syncthreads();
        s[t] += x;
        __syncthreads();
    }
    if (t < NBUCK) bbase[t] = s[t] - v;  // exclusive
    if (t == 0) row_start[NODES] = EDGES;
}

__global__ __launch_bounds__(1024) void bucket_build(const int2* __restrict__ temp,
                                                     const int* __restrict__ gcur,
                                                     const int* __restrict__ bbase,
                                                     int* __restrict__ row_start,
                                                     float* __restrict__ dis,
                                                     int* __restrict__ esrc) {
    __shared__ int cnt[BNODES];
    __shared__ int offs[BNODES];
    __shared__ int cur[BNODES];
    const int b = blockIdx.x;
    const int tid = threadIdx.x;
    const int size = gcur[b];
    const int gbase = bbase[b];

    if (tid < BNODES) cnt[tid] = 0;
    __syncthreads();

    for (int i = tid; i < size; i += 1024) {
        int2 v = temp[(size_t)b * BCAP + i];
        atomicAdd(&cnt[v.y], 1);
    }
    __syncthreads();

    if (tid < BNODES) offs[tid] = cnt[tid];
    __syncthreads();
    for (int d = 1; d < BNODES; d <<= 1) {
        int x = 0;
        if (tid < BNODES && tid >= d) x = offs[tid - d];
        __syncthreads();
        if (tid < BNODES) offs[tid] += x;
        __syncthreads();
    }
    if (tid < BNODES) {
        int excl = offs[tid] - cnt[tid];
        cur[tid] = excl;
        int v = b * BNODES + tid;
        if (v < NODES) {
            row_start[v] = gbase + excl;
            dis[v] = rsqrtf((float)(cnt[tid] + 1));  // +1 self-loop
        }
    }
    __syncthreads();

    for (int i = tid; i < size; i += 1024) {
        int2 v = temp[(size_t)b * BCAP + i];
        int pos = gbase + atomicAdd(&cur[v.y], 1);
        esrc[pos] = v.x;
    }
}

// ---------------------------------------------------------------------------
// W prep: split f32 W[K=128][NCOL] into hi/lo bf16, fragment-major layout
// ---------------------------------------------------------------------------

template <int NCOL>
__global__ __launch_bounds__(256) void w_prep(const float* __restrict__ W,
                                              unsigned short* __restrict__ wh,
                                              unsigned short* __restrict__ wl) {
    constexpr int NCT = NCOL / 16;
    constexpr int FRAGS = 4 * NCT * 64;
    int idx = blockIdx.x * 256 + threadIdx.x;
    if (idx >= FRAGS) return;
    int lane = idx & 63;
    int rem = idx >> 6;
    int ct = rem % NCT;
    int kt = rem / NCT;
    int kbase = kt * 32 + ((lane >> 4) * 8);
    int c = ct * 16 + (lane & 15);
#pragma unroll
    for (int i = 0; i < 8; i++) {
        float v = W[(size_t)(kbase + i) * NCOL + c];
        unsigned short hi = f2bf(v);
        unsigned short lo = f2bf(v - bf2f(hi));
        wh[(size_t)idx * 8 + i] = hi;
        wl[(size_t)idx * 8 + i] = lo;
    }
}

// ---------------------------------------------------------------------------
// GEMM via MFMA 16x16x32 bf16, split-precision (xh@Wh + xl@Wh + xh@Wl)
// ---------------------------------------------------------------------------

template <int NCOL, bool IN_HALF>
__global__ __launch_bounds__(512) void gemm_mfma(const void* __restrict__ Xv,
                                                 const unsigned short* __restrict__ wh,
                                                 const unsigned short* __restrict__ wl,
                                                 const float* __restrict__ dis,
                                                 unsigned short* __restrict__ H) {
    constexpr int NCT = NCOL / 16;
    constexpr int FRAGS = 4 * NCT * 64;  // 2048 (NCOL=128) or 1024 (NCOL=64)
    __shared__ unsigned short s_wh[FRAGS * 8];
    __shared__ unsigned short s_wl[FRAGS * 8];

    const int tid = threadIdx.x;
    const int wave = tid >> 6;
    const int lane = tid & 63;

    const int row0 = blockIdx.x * 128 + wave * 16 + (lane & 15);
    const bool active = (blockIdx.x * 128 + wave * 16) < NODES;  // wave-uniform

    // prefetch A: per ktile, lane reads 8 contiguous elements of its row
    float xs[4][8];
    if (active) {
        if constexpr (IN_HALF) {
            const unsigned short* xrow = (const unsigned short*)Xv + (size_t)row0 * 128 + ((lane >> 4) * 8);
#pragma unroll
            for (int kt = 0; kt < 4; kt++) {
                short8 raw = *(const short8*)(xrow + kt * 32);
#pragma unroll
                for (int i = 0; i < 8; i++) xs[kt][i] = h2f((unsigned short)raw[i]);
            }
        } else {
            const float* xrow = (const float*)Xv + (size_t)row0 * 128 + ((lane >> 4) * 8);
#pragma unroll
            for (int kt = 0; kt < 4; kt++) {
                float4 a = *(const float4*)(xrow + kt * 32);
                float4 b = *(const float4*)(xrow + kt * 32 + 4);
                xs[kt][0] = a.x; xs[kt][1] = a.y; xs[kt][2] = a.z; xs[kt][3] = a.w;
                xs[kt][4] = b.x; xs[kt][5] = b.y; xs[kt][6] = b.z; xs[kt][7] = b.w;
            }
        }
    }

    // stage packed W into LDS (linear, 16B per lane per round)
    constexpr int ROUNDS = (FRAGS * 16) / (512 * 16);  // 4 or 2
#pragma unroll
    for (int j = 0; j < ROUNDS; j++) {
        __builtin_amdgcn_global_load_lds((const unsigned int*)((const char*)wh + ((size_t)tid + j * 512) * 16),
                                         (unsigned int*)(s_wh + ((size_t)tid + j * 512) * 8), 16, 0, 0);
        __builtin_amdgcn_global_load_lds((const unsigned int*)((const char*)wl + ((size_t)tid + j * 512) * 16),
                                         (unsigned int*)(s_wl + ((size_t)tid + j * 512) * 8), 16, 0, 0);
    }
    __syncthreads();

    if (!active) return;

    // convert A to bf16 hi/lo fragments
    short8 ah[4], al[4];
#pragma unroll
    for (int kt = 0; kt < 4; kt++) {
#pragma unroll
        for (int i = 0; i < 8; i++) {
            unsigned short hi = f2bf(xs[kt][i]);
            unsigned short lo = f2bf(xs[kt][i] - bf2f(hi));
            ah[kt][i] = (short)hi;
            al[kt][i] = (short)lo;
        }
    }

    f32x4 acc[NCT];
#pragma unroll
    for (int ct = 0; ct < NCT; ct++) acc[ct] = (f32x4){0.f, 0.f, 0.f, 0.f};

#pragma unroll
    for (int kt = 0; kt < 4; kt++) {
#pragma unroll
        for (int ct = 0; ct < NCT; ct++) {
            const int fo = ((kt * NCT + ct) * 64 + lane) * 8;
            short8 bh = *(const short8*)&s_wh[fo];
            short8 bl = *(const short8*)&s_wl[fo];
            acc[ct] = __builtin_amdgcn_mfma_f32_16x16x32_bf16(ah[kt], bh, acc[ct], 0, 0, 0);
            acc[ct] = __builtin_amdgcn_mfma_f32_16x16x32_bf16(al[kt], bh, acc[ct], 0, 0, 0);
            acc[ct] = __builtin_amdgcn_mfma_f32_16x16x32_bf16(ah[kt], bl, acc[ct], 0, 0, 0);
        }
    }

    // D layout: col = lane&15, row = (lane>>4)*4 + reg
    const int rbase = blockIdx.x * 128 + wave * 16 + ((lane >> 4) * 4);
    float d[4];
#pragma unroll
    for (int r = 0; r < 4; r++) d[r] = dis[rbase + r];
#pragma unroll
    for (int ct = 0; ct < NCT; ct++) {
#pragma unroll
        for (int r = 0; r < 4; r++) {
            H[(size_t)(rbase + r) * NCOL + ct * 16 + (lane & 15)] = f2h_bits(acc[ct][r] * d[r]);
        }
    }
}

// ---------------------------------------------------------------------------
// Aggregation v3 (fp16 H): one node per GL-lane group (GL=16 for C=128,
// GL=8 for C=64); group's lanes cover the full row with uint4 (16B/lane).
// 4-8 independent node chains per wave, no cross-lane ops. 4-deep edge
// unroll with clamped-index + weight-FMA tail; next-4 idx prefetched.
//   OUT[v] = act( dis[v] * (sum_{CSR(v)} H[src] + H[v]) + b )
// ---------------------------------------------------------------------------

template <int C, bool RELU, bool OUT_HALF>
__global__ __launch_bounds__(256, 8) void agg_v3(const unsigned short* __restrict__ H,
                                                 const int* __restrict__ row_start,
                                                 const int* __restrict__ edge_src,
                                                 const float* __restrict__ dis,
                                                 const float* __restrict__ bias,
                                                 void* __restrict__ OUT) {
    constexpr int GL = (C == 128) ? 16 : 8;  // lanes per group (row = GL*16B)
    constexpr int GPW = 64 / GL;             // groups (nodes) per wave
    constexpr int RQ = C / 8;                // row length in uint4 (fp16)

    const int lane = threadIdx.x & 63;
    const int sub = lane & (GL - 1);
    const int grp = lane >> ((C == 128) ? 4 : 3);
    const int wid = (blockIdx.x * 256 + threadIdx.x) >> 6;
    const int v = wid * GPW + grp;
    if (v >= NODES) return;

    const uint4* __restrict__ Hq = (const uint4*)H;

    const int e0 = row_start[v];
    const int e1 = row_start[v + 1];
    const float d = dis[v];

    // per-lane bias (channels sub*8 .. sub*8+7)
    const float4 ba = ((const float4*)bias)[sub * 2];
    const float4 bb = ((const float4*)bias)[sub * 2 + 1];

    // self row
    uint4 gs = Hq[(size_t)v * RQ + sub];

    // first 4 edge indices (group-uniform values in VGPRs; no readlane needed)
    int i0 = edge_src[min(e0 + 0, EDGES - 1)];
    int i1 = edge_src[min(e0 + 1, EDGES - 1)];
    int i2 = edge_src[min(e0 + 2, EDGES - 1)];
    int i3 = edge_src[min(e0 + 3, EDGES - 1)];

    float a0, a1, a2, a3, a4, a5, a6, a7;
    {
        float2 f0 = h2f2(gs.x), f1 = h2f2(gs.y), f2 = h2f2(gs.z), f3 = h2f2(gs.w);
        a0 = f0.x; a1 = f0.y; a2 = f1.x; a3 = f1.y;
        a4 = f2.x; a5 = f2.y; a6 = f3.x; a7 = f3.y;
    }

    for (int k = e0; k < e1; k += 4) {
        // gathers for edges k..k+3 (one full row per group per instruction)
        uint4 g0 = Hq[(size_t)i0 * RQ + sub];
        uint4 g1 = Hq[(size_t)i1 * RQ + sub];
        uint4 g2 = Hq[(size_t)i2 * RQ + sub];
        uint4 g3 = Hq[(size_t)i3 * RQ + sub];
        // prefetch next 4 indices while gathers are in flight
        i0 = edge_src[min(k + 4, EDGES - 1)];
        i1 = edge_src[min(k + 5, EDGES - 1)];
        i2 = edge_src[min(k + 6, EDGES - 1)];
        i3 = edge_src[min(k + 7, EDGES - 1)];
        // tail weights (k+0 always valid inside loop)
        const float w1 = (k + 1 < e1) ? 1.f : 0.f;
        const float w2 = (k + 2 < e1) ? 1.f : 0.f;
        const float w3 = (k + 3 < e1) ? 1.f : 0.f;
#define ACC(G, W)                                                        \
        {                                                                \
            float2 f0 = h2f2(G.x), f1 = h2f2(G.y);                       \
            float2 f2 = h2f2(G.z), f3 = h2f2(G.w);                       \
            a0 = fmaf(f0.x, W, a0); a1 = fmaf(f0.y, W, a1);              \
            a2 = fmaf(f1.x, W, a2); a3 = fmaf(f1.y, W, a3);              \
            a4 = fmaf(f2.x, W, a4); a5 = fmaf(f2.y, W, a5);              \
            a6 = fmaf(f3.x, W, a6); a7 = fmaf(f3.y, W, a7);              \
        }
        ACC(g0, 1.f)
        ACC(g1, w1)
        ACC(g2, w2)
        ACC(g3, w3)
#undef ACC
    }

    // epilogue: scale, bias, activation
    float o0 = fmaf(a0, d, ba.x);
    float o1 = fmaf(a1, d, ba.y);
    float o2 = fmaf(a2, d, ba.z);
    float o3 = fmaf(a3, d, ba.w);
    float o4 = fmaf(a4, d, bb.x);
    float o5 = fmaf(a5, d, bb.y);
    float o6 = fmaf(a6, d, bb.z);
    float o7 = fmaf(a7, d, bb.w);
    if constexpr (RELU) {
        o0 = fmaxf(o0, 0.f); o1 = fmaxf(o1, 0.f);
        o2 = fmaxf(o2, 0.f); o3 = fmaxf(o3, 0.f);
        o4 = fmaxf(o4, 0.f); o5 = fmaxf(o5, 0.f);
        o6 = fmaxf(o6, 0.f); o7 = fmaxf(o7, 0.f);
    }

    if constexpr (OUT_HALF) {
        uint4 o;
        o.x = __builtin_bit_cast(unsigned, __float22half2_rn(make_float2(o0, o1)));
        o.y = __builtin_bit_cast(unsigned, __float22half2_rn(make_float2(o2, o3)));
        o.z = __builtin_bit_cast(unsigned, __float22half2_rn(make_float2(o4, o5)));
        o.w = __builtin_bit_cast(unsigned, __float22half2_rn(make_float2(o6, o7)));
        ((uint4*)OUT)[(size_t)v * RQ + sub] = o;
    } else {
        float4 oa, ob;
        oa.x = o0; oa.y = o1; oa.z = o2; oa.w = o3;
        ob.x = o4; ob.y = o5; ob.z = o6; ob.w = o7;
        float* outp = (float*)OUT + (size_t)v * C + sub * 8;
        *(float4*)(outp) = oa;
        *(float4*)(outp + 4) = ob;
    }
}

// ---------------------------------------------------------------------------

extern "C" void kernel_launch(void* const* d_in, const int* in_sizes, int n_in,
                              void* d_out, int out_size, void* d_ws, size_t ws_size,
                              hipStream_t stream) {
    const float* x   = (const float*)d_in[0];
    const int* eidx  = (const int*)d_in[1];
    const float* W1  = (const float*)d_in[2];
    const float* b1  = (const float*)d_in[3];
    const float* W2  = (const float*)d_in[4];
    const float* b2  = (const float*)d_in[5];
    float* out = (float*)d_out;

    const int* erow = eidx;          // sources
    const int* ecol = eidx + EDGES;  // targets

    // workspace carve-up (256B aligned)
    char* w = (char*)d_ws;
    size_t off = 0;
    auto alloc = [&](size_t bytes) -> void* {
        void* p = w + off;
        off += (bytes + 255) & ~(size_t)255;
        return p;
    };
    float* dis     = (float*)alloc((size_t)NODES * 4);
    int*   rowst   = (int*)alloc((size_t)(NODES + 1) * 4);
    int*   esrc    = (int*)alloc((size_t)EDGES * 4);
    int*   gcur    = (int*)alloc(NBUCK * 4);
    int*   bbase   = (int*)alloc(NBUCK * 4);
    int2*  temp    = (int2*)alloc((size_t)NBUCK * BCAP * 8);
    unsigned short* wh1 = (unsigned short*)alloc(2048 * 8 * 2);
    unsigned short* wl1 = (unsigned short*)alloc(2048 * 8 * 2);
    unsigned short* wh2 = (unsigned short*)alloc(1024 * 8 * 2);
    unsigned short* wl2 = (unsigned short*)alloc(1024 * 8 * 2);
    unsigned short* bufA = (unsigned short*)alloc((size_t)NODES * 128 * 2);  // h1' / h2' (fp16)
    unsigned short* bufB = (unsigned short*)alloc((size_t)NODES * 128 * 2);  // relu(out1) (fp16)

    hipMemsetAsync(gcur, 0, NBUCK * 4, stream);

    // CSR build (bucketed, dense writes)
    bucket_scatter<<<(EDGES + 1023) / 1024, 1024, 0, stream>>>(erow, ecol, gcur, temp);
    bucket_scan<<<1, 256, 0, stream>>>(gcur, bbase, rowst);
    bucket_build<<<NBUCK, 1024, 0, stream>>>(temp, gcur, bbase, rowst, dis, esrc);

    w_prep<128><<<8, 256, 0, stream>>>(W1, wh1, wl1);
    w_prep<64><<<4, 256, 0, stream>>>(W2, wh2, wl2);

    const int GB = (NODES + 127) / 128;  // 782

    // layer 1: h1' = (x @ W1)*dis (fp16) ; out1 = relu(dis*(agg+self)+b1) (fp16)
    gemm_mfma<128, false><<<GB, 512, 0, stream>>>(x, wh1, wl1, dis, bufA);
    agg_v3<128, true, true><<<(NODES + 15) / 16, 256, 0, stream>>>(bufA, rowst, esrc, dis, b1, bufB);

    // layer 2: h2' = (out1 @ W2)*dis (fp16) ; out = dis*(agg+self)+b2 (f32)
    gemm_mfma<64, true><<<GB, 512, 0, stream>>>(bufB, wh2, wl2, dis, bufA);
    agg_v3<64, false, false><<<(NODES + 31) / 32, 256, 0, stream>>>(bufA, rowst, esrc, dis, b2, out);
}

// Round 7
// 194.029 us; speedup vs baseline: 2.8814x; 1.0062x over previous
//
#include <hip/hip_runtime.h>
#include <hip/hip_fp16.h>

#define NODES 100000
#define EDGES 1600000

#define BSHIFT 9
#define BNODES 512                                   // nodes per bucket
#define NBUCK ((NODES + BNODES - 1) / BNODES)        // 196
#define BCAP 10240                                   // max edges per bucket (avg 8163, +22 sigma)

typedef __attribute__((ext_vector_type(8))) short short8;
typedef __attribute__((ext_vector_type(4))) float f32x4;
typedef unsigned short ushort_t;

// ---------------------------------------------------------------------------
// bf16 / fp16 helpers
// ---------------------------------------------------------------------------
__device__ inline unsigned short f2bf(float f) {
    unsigned u = __builtin_bit_cast(unsigned, f);
    u = u + 0x7fff + ((u >> 16) & 1);
    return (unsigned short)(u >> 16);
}
__device__ inline float bf2f(unsigned short h) {
    unsigned u = ((unsigned)h) << 16;
    return __builtin_bit_cast(float, u);
}
__device__ inline unsigned short f2h_bits(float f) {
    __half h = __float2half_rn(f);
    return __builtin_bit_cast(unsigned short, h);
}
__device__ inline float h2f(unsigned short bits) {
    return __half2float(__builtin_bit_cast(__half, bits));
}
__device__ inline float2 h2f2(unsigned int bits) {
    __half2 h = __builtin_bit_cast(__half2, bits);
    return __half22float2(h);
}

// ---------------------------------------------------------------------------
// prep: blocks 0-7 -> W1 split hi/lo bf16 fragment-major (for MFMA gemm1);
//       block 8   -> W2 f32->fp16 row-major [128][64] + zero gcur
// ---------------------------------------------------------------------------

__global__ __launch_bounds__(256) void prep_kernel(const float* __restrict__ W1,
                                                   const float* __restrict__ W2,
                                                   unsigned short* __restrict__ wh,
                                                   unsigned short* __restrict__ wl,
                                                   unsigned short* __restrict__ w2h,
                                                   int* __restrict__ gcur) {
    const int tid = threadIdx.x;
    if (blockIdx.x < 8) {
        // W1 fragment prep: k = kt*32 + (lane>>4)*8 + i, c = ct*16 + (lane&15)
        constexpr int NCOL = 128;
        constexpr int NCT = NCOL / 16;
        int idx = blockIdx.x * 256 + tid;  // frag id in [0, 2048)
        int lane = idx & 63;
        int rem = idx >> 6;
        int ct = rem % NCT;
        int kt = rem / NCT;
        int kbase = kt * 32 + ((lane >> 4) * 8);
        int c = ct * 16 + (lane & 15);
#pragma unroll
        for (int i = 0; i < 8; i++) {
            float v = W1[(size_t)(kbase + i) * NCOL + c];
            unsigned short hi = f2bf(v);
            unsigned short lo = f2bf(v - bf2f(hi));
            wh[(size_t)idx * 8 + i] = hi;
            wl[(size_t)idx * 8 + i] = lo;
        }
    } else {
        // W2 [128][64] f32 -> fp16 flat (row-major preserved)
#pragma unroll
        for (int i = 0; i < 32; i++) {
            int idx = i * 256 + tid;
            w2h[idx] = f2h_bits(W2[idx]);
        }
        if (tid < NBUCK) gcur[tid] = 0;
    }
}

// ---------------------------------------------------------------------------
// CSR build, bucketed (dense writes)
// ---------------------------------------------------------------------------

__global__ __launch_bounds__(1024) void bucket_scatter(const int* __restrict__ row,
                                                       const int* __restrict__ col,
                                                       int* __restrict__ gcur,
                                                       int2* __restrict__ temp) {
    __shared__ int hist[NBUCK];
    __shared__ int base[NBUCK];
    const int tid = threadIdx.x;
    for (int i = tid; i < NBUCK; i += 1024) hist[i] = 0;
    __syncthreads();

    const int e = blockIdx.x * 1024 + tid;
    const bool valid = e < EDGES;
    int b = 0, rank = 0, src = 0, c = 0;
    if (valid) {
        c = col[e];
        src = row[e];
        b = c >> BSHIFT;
        rank = atomicAdd(&hist[b], 1);
    }
    __syncthreads();
    for (int i = tid; i < NBUCK; i += 1024) {
        int h = hist[i];
        base[i] = h ? atomicAdd(&gcur[i], h) : 0;
    }
    __syncthreads();
    if (valid) {
        int pos = base[b] + rank;
        int2 v;
        v.x = src;
        v.y = c & (BNODES - 1);
        temp[(size_t)b * BCAP + pos] = v;
    }
}

// bucket_build with inline 196-wide scan of gcur (replaces bucket_scan kernel)
__global__ __launch_bounds__(1024) void bucket_build(const int2* __restrict__ temp,
                                                     const int* __restrict__ gcur,
                                                     int* __restrict__ row_start,
                                                     float* __restrict__ dis,
                                                     int* __restrict__ esrc) {
    __shared__ int cnt[BNODES];
    __shared__ int offs[BNODES];
    __shared__ int cur[BNODES];
    __shared__ int ssc[256];
    const int b = blockIdx.x;
    const int tid = threadIdx.x;

    // inclusive scan of bucket sizes (tiny: 196 ints)
    if (tid < 256) ssc[tid] = (tid < NBUCK) ? gcur[tid] : 0;
    __syncthreads();
    for (int d = 1; d < 256; d <<= 1) {
        int x = (tid < 256 && tid >= d) ? ssc[tid - d] : 0;
        __syncthreads();
        if (tid < 256) ssc[tid] += x;
        __syncthreads();
    }
    const int size = gcur[b];
    const int gbase = ssc[b] - size;  // exclusive prefix
    if (b == 0 && tid == 0) row_start[NODES] = EDGES;

    if (tid < BNODES) cnt[tid] = 0;
    __syncthreads();

    for (int i = tid; i < size; i += 1024) {
        int2 v = temp[(size_t)b * BCAP + i];
        atomicAdd(&cnt[v.y], 1);
    }
    __syncthreads();

    if (tid < BNODES) offs[tid] = cnt[tid];
    __syncthreads();
    for (int d = 1; d < BNODES; d <<= 1) {
        int x = 0;
        if (tid < BNODES && tid >= d) x = offs[tid - d];
        __syncthreads();
        if (tid < BNODES) offs[tid] += x;
        __syncthreads();
    }
    if (tid < BNODES) {
        int excl = offs[tid] - cnt[tid];
        cur[tid] = excl;
        int v = b * BNODES + tid;
        if (v < NODES) {
            row_start[v] = gbase + excl;
            dis[v] = rsqrtf((float)(cnt[tid] + 1));  // +1 self-loop
        }
    }
    __syncthreads();

    for (int i = tid; i < size; i += 1024) {
        int2 v = temp[(size_t)b * BCAP + i];
        int pos = gbase + atomicAdd(&cur[v.y], 1);
        esrc[pos] = v.x;
    }
}

// ---------------------------------------------------------------------------
// GEMM via MFMA 16x16x32 bf16, split-precision (xh@Wh + xl@Wh + xh@Wl)
//   H[r][:] = (X[r][:] @ W1) * dis[r],  fp16 out
// ---------------------------------------------------------------------------

__global__ __launch_bounds__(512) void gemm_mfma(const float* __restrict__ X,
                                                 const unsigned short* __restrict__ wh,
                                                 const unsigned short* __restrict__ wl,
                                                 const float* __restrict__ dis,
                                                 unsigned short* __restrict__ H) {
    constexpr int NCOL = 128;
    constexpr int NCT = NCOL / 16;
    constexpr int FRAGS = 4 * NCT * 64;  // 2048
    __shared__ unsigned short s_wh[FRAGS * 8];
    __shared__ unsigned short s_wl[FRAGS * 8];

    const int tid = threadIdx.x;
    const int wave = tid >> 6;
    const int lane = tid & 63;

    const int row0 = blockIdx.x * 128 + wave * 16 + (lane & 15);
    const bool active = (blockIdx.x * 128 + wave * 16) < NODES;  // wave-uniform

    float xs[4][8];
    if (active) {
        const float* xrow = X + (size_t)row0 * 128 + ((lane >> 4) * 8);
#pragma unroll
        for (int kt = 0; kt < 4; kt++) {
            float4 a = *(const float4*)(xrow + kt * 32);
            float4 b = *(const float4*)(xrow + kt * 32 + 4);
            xs[kt][0] = a.x; xs[kt][1] = a.y; xs[kt][2] = a.z; xs[kt][3] = a.w;
            xs[kt][4] = b.x; xs[kt][5] = b.y; xs[kt][6] = b.z; xs[kt][7] = b.w;
        }
    }

    constexpr int ROUNDS = (FRAGS * 16) / (512 * 16);  // 4
#pragma unroll
    for (int j = 0; j < ROUNDS; j++) {
        __builtin_amdgcn_global_load_lds((const unsigned int*)((const char*)wh + ((size_t)tid + j * 512) * 16),
                                         (unsigned int*)(s_wh + ((size_t)tid + j * 512) * 8), 16, 0, 0);
        __builtin_amdgcn_global_load_lds((const unsigned int*)((const char*)wl + ((size_t)tid + j * 512) * 16),
                                         (unsigned int*)(s_wl + ((size_t)tid + j * 512) * 8), 16, 0, 0);
    }
    __syncthreads();

    if (!active) return;

    short8 ah[4], al[4];
#pragma unroll
    for (int kt = 0; kt < 4; kt++) {
#pragma unroll
        for (int i = 0; i < 8; i++) {
            unsigned short hi = f2bf(xs[kt][i]);
            unsigned short lo = f2bf(xs[kt][i] - bf2f(hi));
            ah[kt][i] = (short)hi;
            al[kt][i] = (short)lo;
        }
    }

    f32x4 acc[NCT];
#pragma unroll
    for (int ct = 0; ct < NCT; ct++) acc[ct] = (f32x4){0.f, 0.f, 0.f, 0.f};

#pragma unroll
    for (int kt = 0; kt < 4; kt++) {
#pragma unroll
        for (int ct = 0; ct < NCT; ct++) {
            const int fo = ((kt * NCT + ct) * 64 + lane) * 8;
            short8 bh = *(const short8*)&s_wh[fo];
            short8 bl = *(const short8*)&s_wl[fo];
            acc[ct] = __builtin_amdgcn_mfma_f32_16x16x32_bf16(ah[kt], bh, acc[ct], 0, 0, 0);
            acc[ct] = __builtin_amdgcn_mfma_f32_16x16x32_bf16(al[kt], bh, acc[ct], 0, 0, 0);
            acc[ct] = __builtin_amdgcn_mfma_f32_16x16x32_bf16(ah[kt], bl, acc[ct], 0, 0, 0);
        }
    }

    // D layout: col = lane&15, row = (lane>>4)*4 + reg
    const int rbase = blockIdx.x * 128 + wave * 16 + ((lane >> 4) * 4);
    float d[4];
#pragma unroll
    for (int r = 0; r < 4; r++) d[r] = dis[rbase + r];
#pragma unroll
    for (int ct = 0; ct < NCT; ct++) {
#pragma unroll
        for (int r = 0; r < 4; r++) {
            H[(size_t)(rbase + r) * NCOL + ct * 16 + (lane & 15)] = f2h_bits(acc[ct][r] * d[r]);
        }
    }
}

// ---------------------------------------------------------------------------
// FUSED agg1 + gemm2 (C=128 in, 64 out):
//   phase 1 (gather): out1[v] = relu(dis[v]*(sum_{CSR(v)} H[s] + H[v]) + b1)
//                     -> f32 LDS  (16 nodes/block; GL=16 lanes/node, uint4 rows)
//   phase 2 (matvec): H2[v] = (out1[v] @ W2) * dis[v]   (W2 fp16 in LDS)
// Exact grid: 6250 blocks x 16 nodes = 100000 (no tail, safe barrier).
// ---------------------------------------------------------------------------

__global__ __launch_bounds__(256) void agg_fused(const unsigned short* __restrict__ H,
                                                 const int* __restrict__ row_start,
                                                 const int* __restrict__ edge_src,
                                                 const float* __restrict__ dis,
                                                 const float* __restrict__ b1,
                                                 const unsigned short* __restrict__ w2h,
                                                 unsigned short* __restrict__ H2) {
    __shared__ float h_lds[16][128];            // 8 KB
    __shared__ unsigned short w2_lds[128 * 64]; // 16 KB

    const int tid = threadIdx.x;
    const int lane = tid & 63;
    const int sub = lane & 15;
    const int grp = lane >> 4;
    const int nl = (tid >> 6) * 4 + grp;        // node_local in [0,16)
    const int v = blockIdx.x * 16 + nl;

    // stage W2 fp16 (16KB, linear, 16B per lane per round)
#pragma unroll
    for (int j = 0; j < 4; j++) {
        __builtin_amdgcn_global_load_lds((const unsigned int*)((const char*)w2h + ((size_t)tid + j * 256) * 16),
                                         (unsigned int*)w2_lds + ((size_t)tid + j * 256) * 4, 16, 0, 0);
    }

    const uint4* __restrict__ Hq = (const uint4*)H;
    const int e0 = row_start[v];
    const int e1 = row_start[v + 1];
    const float d = dis[v];

    const float4 ba = ((const float4*)b1)[sub * 2];
    const float4 bb = ((const float4*)b1)[sub * 2 + 1];

    uint4 gs = Hq[(size_t)v * 16 + sub];  // self row

    int i0 = edge_src[min(e0 + 0, EDGES - 1)];
    int i1 = edge_src[min(e0 + 1, EDGES - 1)];
    int i2 = edge_src[min(e0 + 2, EDGES - 1)];
    int i3 = edge_src[min(e0 + 3, EDGES - 1)];

    float a0, a1, a2, a3, a4, a5, a6, a7;
    {
        float2 f0 = h2f2(gs.x), f1 = h2f2(gs.y), f2 = h2f2(gs.z), f3 = h2f2(gs.w);
        a0 = f0.x; a1 = f0.y; a2 = f1.x; a3 = f1.y;
        a4 = f2.x; a5 = f2.y; a6 = f3.x; a7 = f3.y;
    }

    for (int k = e0; k < e1; k += 4) {
        uint4 g0 = Hq[(size_t)i0 * 16 + sub];
        uint4 g1 = Hq[(size_t)i1 * 16 + sub];
        uint4 g2 = Hq[(size_t)i2 * 16 + sub];
        uint4 g3 = Hq[(size_t)i3 * 16 + sub];
        i0 = edge_src[min(k + 4, EDGES - 1)];
        i1 = edge_src[min(k + 5, EDGES - 1)];
        i2 = edge_src[min(k + 6, EDGES - 1)];
        i3 = edge_src[min(k + 7, EDGES - 1)];
        const float w1 = (k + 1 < e1) ? 1.f : 0.f;
        const float w2 = (k + 2 < e1) ? 1.f : 0.f;
        const float w3 = (k + 3 < e1) ? 1.f : 0.f;
#define ACC(G, W)                                                        \
        {                                                                \
            float2 f0 = h2f2(G.x), f1 = h2f2(G.y);                       \
            float2 f2 = h2f2(G.z), f3 = h2f2(G.w);                       \
            a0 = fmaf(f0.x, W, a0); a1 = fmaf(f0.y, W, a1);              \
            a2 = fmaf(f1.x, W, a2); a3 = fmaf(f1.y, W, a3);              \
            a4 = fmaf(f2.x, W, a4); a5 = fmaf(f2.y, W, a5);              \
            a6 = fmaf(f3.x, W, a6); a7 = fmaf(f3.y, W, a7);              \
        }
        ACC(g0, 1.f)
        ACC(g1, w1)
        ACC(g2, w2)
        ACC(g3, w3)
#undef ACC
    }

    // out1 epilogue -> LDS (f32, full precision)
    {
        float4 oa, ob;
        oa.x = fmaf(a0, d, ba.x); oa.y = fmaf(a1, d, ba.y);
        oa.z = fmaf(a2, d, ba.z); oa.w = fmaf(a3, d, ba.w);
        ob.x = fmaf(a4, d, bb.x); ob.y = fmaf(a5, d, bb.y);
        ob.z = fmaf(a6, d, bb.z); ob.w = fmaf(a7, d, bb.w);
        oa.x = fmaxf(oa.x, 0.f); oa.y = fmaxf(oa.y, 0.f);
        oa.z = fmaxf(oa.z, 0.f); oa.w = fmaxf(oa.w, 0.f);
        ob.x = fmaxf(ob.x, 0.f); ob.y = fmaxf(ob.y, 0.f);
        ob.z = fmaxf(ob.z, 0.f); ob.w = fmaxf(ob.w, 0.f);
        *(float4*)&h_lds[nl][sub * 8] = oa;
        *(float4*)&h_lds[nl][sub * 8 + 4] = ob;
    }
    __syncthreads();  // h_lds ready + W2 staged

    // matvec: lane computes out channels j0 = sub*4 .. +3 for node nl
    float c0 = 0.f, c1 = 0.f, c2 = 0.f, c3 = 0.f;
#pragma unroll 8
    for (int k4 = 0; k4 < 32; k4++) {
        float4 s = *(const float4*)&h_lds[nl][k4 * 4];
        const unsigned short* wrow = &w2_lds[(k4 * 4) * 64 + sub * 4];
        uint2 w0 = *(const uint2*)(wrow);
        uint2 w1 = *(const uint2*)(wrow + 64);
        uint2 w2 = *(const uint2*)(wrow + 128);
        uint2 w3 = *(const uint2*)(wrow + 192);
#define MV(S, WW)                                                        \
        {                                                                \
            float2 p0 = h2f2(WW.x), p1 = h2f2(WW.y);                     \
            c0 = fmaf(S, p0.x, c0); c1 = fmaf(S, p0.y, c1);              \
            c2 = fmaf(S, p1.x, c2); c3 = fmaf(S, p1.y, c3);              \
        }
        MV(s.x, w0)
        MV(s.y, w1)
        MV(s.z, w2)
        MV(s.w, w3)
#undef MV
    }

    // h2' = matvec * dis[v]  (fp16 out, coalesced 8B/lane)
    uint2 o;
    o.x = __builtin_bit_cast(unsigned, __float22half2_rn(make_float2(c0 * d, c1 * d)));
    o.y = __builtin_bit_cast(unsigned, __float22half2_rn(make_float2(c2 * d, c3 * d)));
    ((uint2*)H2)[(size_t)v * 16 + sub] = o;
}

// ---------------------------------------------------------------------------
// Aggregation layer 2 (64ch fp16 in, f32 out): GL=8 lanes/node, uint4 rows
// ---------------------------------------------------------------------------

__global__ __launch_bounds__(256, 8) void agg_l2(const unsigned short* __restrict__ H,
                                                 const int* __restrict__ row_start,
                                                 const int* __restrict__ edge_src,
                                                 const float* __restrict__ dis,
                                                 const float* __restrict__ bias,
                                                 float* __restrict__ OUT) {
    constexpr int GL = 8;
    constexpr int GPW = 8;
    constexpr int RQ = 8;  // row length in uint4

    const int lane = threadIdx.x & 63;
    const int sub = lane & (GL - 1);
    const int grp = lane >> 3;
    const int wid = (blockIdx.x * 256 + threadIdx.x) >> 6;
    const int v = wid * GPW + grp;

    const uint4* __restrict__ Hq = (const uint4*)H;

    const int e0 = row_start[v];
    const int e1 = row_start[v + 1];
    const float d = dis[v];

    const float4 ba = ((const float4*)bias)[sub * 2];
    const float4 bb = ((const float4*)bias)[sub * 2 + 1];

    uint4 gs = Hq[(size_t)v * RQ + sub];

    int i0 = edge_src[min(e0 + 0, EDGES - 1)];
    int i1 = edge_src[min(e0 + 1, EDGES - 1)];
    int i2 = edge_src[min(e0 + 2, EDGES - 1)];
    int i3 = edge_src[min(e0 + 3, EDGES - 1)];

    float a0, a1, a2, a3, a4, a5, a6, a7;
    {
        float2 f0 = h2f2(gs.x), f1 = h2f2(gs.y), f2 = h2f2(gs.z), f3 = h2f2(gs.w);
        a0 = f0.x; a1 = f0.y; a2 = f1.x; a3 = f1.y;
        a4 = f2.x; a5 = f2.y; a6 = f3.x; a7 = f3.y;
    }

    for (int k = e0; k < e1; k += 4) {
        uint4 g0 = Hq[(size_t)i0 * RQ + sub];
        uint4 g1 = Hq[(size_t)i1 * RQ + sub];
        uint4 g2 = Hq[(size_t)i2 * RQ + sub];
        uint4 g3 = Hq[(size_t)i3 * RQ + sub];
        i0 = edge_src[min(k + 4, EDGES - 1)];
        i1 = edge_src[min(k + 5, EDGES - 1)];
        i2 = edge_src[min(k + 6, EDGES - 1)];
        i3 = edge_src[min(k + 7, EDGES - 1)];
        const float w1 = (k + 1 < e1) ? 1.f : 0.f;
        const float w2 = (k + 2 < e1) ? 1.f : 0.f;
        const float w3 = (k + 3 < e1) ? 1.f : 0.f;
#define ACC(G, W)                                                        \
        {                                                                \
            float2 f0 = h2f2(G.x), f1 = h2f2(G.y);                       \
            float2 f2 = h2f2(G.z), f3 = h2f2(G.w);                       \
            a0 = fmaf(f0.x, W, a0); a1 = fmaf(f0.y, W, a1);              \
            a2 = fmaf(f1.x, W, a2); a3 = fmaf(f1.y, W, a3);              \
            a4 = fmaf(f2.x, W, a4); a5 = fmaf(f2.y, W, a5);              \
            a6 = fmaf(f3.x, W, a6); a7 = fmaf(f3.y, W, a7);              \
        }
        ACC(g0, 1.f)
        ACC(g1, w1)
        ACC(g2, w2)
        ACC(g3, w3)
#undef ACC
    }

    float4 oa, ob;
    oa.x = fmaf(a0, d, ba.x); oa.y = fmaf(a1, d, ba.y);
    oa.z = fmaf(a2, d, ba.z); oa.w = fmaf(a3, d, ba.w);
    ob.x = fmaf(a4, d, bb.x); ob.y = fmaf(a5, d, bb.y);
    ob.z = fmaf(a6, d, bb.z); ob.w = fmaf(a7, d, bb.w);
    float* outp = OUT + (size_t)v * 64 + sub * 8;
    *(float4*)(outp) = oa;
    *(float4*)(outp + 4) = ob;
}

// ---------------------------------------------------------------------------

extern "C" void kernel_launch(void* const* d_in, const int* in_sizes, int n_in,
                              void* d_out, int out_size, void* d_ws, size_t ws_size,
                              hipStream_t stream) {
    const float* x   = (const float*)d_in[0];
    const int* eidx  = (const int*)d_in[1];
    const float* W1  = (const float*)d_in[2];
    const float* b1  = (const float*)d_in[3];
    const float* W2  = (const float*)d_in[4];
    const float* b2  = (const float*)d_in[5];
    float* out = (float*)d_out;

    const int* erow = eidx;          // sources
    const int* ecol = eidx + EDGES;  // targets

    // workspace carve-up (256B aligned)
    char* w = (char*)d_ws;
    size_t off = 0;
    auto alloc = [&](size_t bytes) -> void* {
        void* p = w + off;
        off += (bytes + 255) & ~(size_t)255;
        return p;
    };
    float* dis     = (float*)alloc((size_t)NODES * 4);
    int*   rowst   = (int*)alloc((size_t)(NODES + 1) * 4);
    int*   esrc    = (int*)alloc((size_t)EDGES * 4);
    int*   gcur    = (int*)alloc(NBUCK * 4);
    int2*  temp    = (int2*)alloc((size_t)NBUCK * BCAP * 8);
    unsigned short* wh1 = (unsigned short*)alloc(2048 * 8 * 2);
    unsigned short* wl1 = (unsigned short*)alloc(2048 * 8 * 2);
    unsigned short* w2h = (unsigned short*)alloc(128 * 64 * 2);
    unsigned short* bufA = (unsigned short*)alloc((size_t)NODES * 128 * 2);  // h1' (fp16)
    unsigned short* bufB = (unsigned short*)alloc((size_t)NODES * 64 * 2);   // h2' (fp16)

    // 1) weight prep + gcur zeroing (blocks 0-7: W1; block 8: W2 + gcur)
    prep_kernel<<<9, 256, 0, stream>>>(W1, W2, wh1, wl1, w2h, gcur);

    // 2) CSR build (bucketed, dense writes; scan inlined in bucket_build)
    bucket_scatter<<<(EDGES + 1023) / 1024, 1024, 0, stream>>>(erow, ecol, gcur, temp);
    bucket_build<<<NBUCK, 1024, 0, stream>>>(temp, gcur, rowst, dis, esrc);

    // 3) layer 1 transform: h1' = (x @ W1) * dis  (fp16)
    const int GB = (NODES + 127) / 128;  // 782
    gemm_mfma<<<GB, 512, 0, stream>>>(x, wh1, wl1, dis, bufA);

    // 4) fused agg1 + gemm2: h2' = (relu(dis*(S h1') + b1) @ W2) * dis  (fp16)
    agg_fused<<<NODES / 16, 256, 0, stream>>>(bufA, rowst, esrc, dis, b1, w2h, bufB);

    // 5) layer 2 aggregation: out = dis*(S h2') + b2  (f32)
    agg_l2<<<NODES / 32, 256, 0, stream>>>(bufB, rowst, esrc, dis, b2, out);
}

// Round 8
// 184.583 us; speedup vs baseline: 3.0289x; 1.0512x over previous
//
#include <hip/hip_runtime.h>
#include <hip/hip_fp16.h>

#define NODES 100000
#define EDGES 1600000

#define BSHIFT 9
#define BNODES 512                                   // nodes per bucket
#define NBUCK ((NODES + BNODES - 1) / BNODES)        // 196
#define BCAP 10240                                   // max edges per bucket (avg 8163)

#define GB 782                                       // gemm1 blocks (128 rows each)
#define SC 1563                                      // scatter blocks (1024 edges each)

typedef __attribute__((ext_vector_type(8))) short short8;
typedef __attribute__((ext_vector_type(4))) float f32x4;

// ---------------------------------------------------------------------------
// bf16 / fp16 helpers
// ---------------------------------------------------------------------------
__device__ inline unsigned short f2bf(float f) {
    unsigned u = __builtin_bit_cast(unsigned, f);
    u = u + 0x7fff + ((u >> 16) & 1);
    return (unsigned short)(u >> 16);
}
__device__ inline float bf2f(unsigned short h) {
    unsigned u = ((unsigned)h) << 16;
    return __builtin_bit_cast(float, u);
}
__device__ inline unsigned short f2h_bits(float f) {
    __half h = __float2half_rn(f);
    return __builtin_bit_cast(unsigned short, h);
}
__device__ inline float h2f(unsigned short bits) {
    return __half2float(__builtin_bit_cast(__half, bits));
}
__device__ inline float2 h2f2(unsigned int bits) {
    __half2 h = __builtin_bit_cast(__half2, bits);
    return __half22float2(h);
}

// ---------------------------------------------------------------------------
// prep: blocks 0-7 -> W1 hi/lo bf16 frags; 8-11 -> W2 hi/lo bf16 frags;
//       block 12 -> zero gcur
// ---------------------------------------------------------------------------

template <int NCOL>
__device__ __forceinline__ void w_frag_prep(const float* __restrict__ W,
                                            unsigned short* __restrict__ wh,
                                            unsigned short* __restrict__ wl,
                                            int idx) {
    constexpr int NCT = NCOL / 16;
    int lane = idx & 63;
    int rem = idx >> 6;
    int ct = rem % NCT;
    int kt = rem / NCT;
    int kbase = kt * 32 + ((lane >> 4) * 8);
    int c = ct * 16 + (lane & 15);
#pragma unroll
    for (int i = 0; i < 8; i++) {
        float v = W[(size_t)(kbase + i) * NCOL + c];
        unsigned short hi = f2bf(v);
        unsigned short lo = f2bf(v - bf2f(hi));
        wh[(size_t)idx * 8 + i] = hi;
        wl[(size_t)idx * 8 + i] = lo;
    }
}

__global__ __launch_bounds__(256) void prep_kernel(const float* __restrict__ W1,
                                                   const float* __restrict__ W2,
                                                   unsigned short* __restrict__ wh1,
                                                   unsigned short* __restrict__ wl1,
                                                   unsigned short* __restrict__ wh2,
                                                   unsigned short* __restrict__ wl2,
                                                   int* __restrict__ gcur) {
    const int tid = threadIdx.x;
    const int b = blockIdx.x;
    if (b < 8) {
        w_frag_prep<128>(W1, wh1, wl1, b * 256 + tid);
    } else if (b < 12) {
        w_frag_prep<64>(W2, wh2, wl2, (b - 8) * 256 + tid);
    } else {
        if (tid < NBUCK) gcur[tid] = 0;
    }
}

// ---------------------------------------------------------------------------
// GEMM body via MFMA 16x16x32 bf16, split-precision: H = X @ W  (fp16 out,
// NO dis fold). Caller supplies LDS for packed W.
// ---------------------------------------------------------------------------

template <int NCOL, bool IN_HALF>
__device__ __forceinline__ void gemm_body(const void* __restrict__ Xv,
                                          const unsigned short* __restrict__ wh,
                                          const unsigned short* __restrict__ wl,
                                          unsigned short* __restrict__ H,
                                          unsigned short* s_wh,
                                          unsigned short* s_wl,
                                          int tid, int bid) {
    constexpr int NCT = NCOL / 16;
    constexpr int FRAGS = 4 * NCT * 64;  // 2048 (128) / 1024 (64)

    const int wave = tid >> 6;
    const int lane = tid & 63;

    const int row0 = bid * 128 + wave * 16 + (lane & 15);
    const bool active = (bid * 128 + wave * 16) < NODES;  // wave-uniform

    float xs[4][8];
    if (active) {
        if constexpr (IN_HALF) {
            const unsigned short* xrow = (const unsigned short*)Xv + (size_t)row0 * 128 + ((lane >> 4) * 8);
#pragma unroll
            for (int kt = 0; kt < 4; kt++) {
                short8 raw = *(const short8*)(xrow + kt * 32);
#pragma unroll
                for (int i = 0; i < 8; i++) xs[kt][i] = h2f((unsigned short)raw[i]);
            }
        } else {
            const float* xrow = (const float*)Xv + (size_t)row0 * 128 + ((lane >> 4) * 8);
#pragma unroll
            for (int kt = 0; kt < 4; kt++) {
                float4 a = *(const float4*)(xrow + kt * 32);
                float4 b = *(const float4*)(xrow + kt * 32 + 4);
                xs[kt][0] = a.x; xs[kt][1] = a.y; xs[kt][2] = a.z; xs[kt][3] = a.w;
                xs[kt][4] = b.x; xs[kt][5] = b.y; xs[kt][6] = b.z; xs[kt][7] = b.w;
            }
        }
    }

    constexpr int ROUNDS = (FRAGS * 16) / (512 * 16);  // 4 or 2
#pragma unroll
    for (int j = 0; j < ROUNDS; j++) {
        __builtin_amdgcn_global_load_lds((const unsigned int*)((const char*)wh + ((size_t)tid + j * 512) * 16),
                                         (unsigned int*)(s_wh + ((size_t)tid + j * 512) * 8), 16, 0, 0);
        __builtin_amdgcn_global_load_lds((const unsigned int*)((const char*)wl + ((size_t)tid + j * 512) * 16),
                                         (unsigned int*)(s_wl + ((size_t)tid + j * 512) * 8), 16, 0, 0);
    }
    __syncthreads();

    if (!active) return;

    short8 ah[4], al[4];
#pragma unroll
    for (int kt = 0; kt < 4; kt++) {
#pragma unroll
        for (int i = 0; i < 8; i++) {
            unsigned short hi = f2bf(xs[kt][i]);
            unsigned short lo = f2bf(xs[kt][i] - bf2f(hi));
            ah[kt][i] = (short)hi;
            al[kt][i] = (short)lo;
        }
    }

    f32x4 acc[NCT];
#pragma unroll
    for (int ct = 0; ct < NCT; ct++) acc[ct] = (f32x4){0.f, 0.f, 0.f, 0.f};

#pragma unroll
    for (int kt = 0; kt < 4; kt++) {
#pragma unroll
        for (int ct = 0; ct < NCT; ct++) {
            const int fo = ((kt * NCT + ct) * 64 + lane) * 8;
            short8 bh = *(const short8*)&s_wh[fo];
            short8 bl = *(const short8*)&s_wl[fo];
            acc[ct] = __builtin_amdgcn_mfma_f32_16x16x32_bf16(ah[kt], bh, acc[ct], 0, 0, 0);
            acc[ct] = __builtin_amdgcn_mfma_f32_16x16x32_bf16(al[kt], bh, acc[ct], 0, 0, 0);
            acc[ct] = __builtin_amdgcn_mfma_f32_16x16x32_bf16(ah[kt], bl, acc[ct], 0, 0, 0);
        }
    }

    // D layout: col = lane&15, row = (lane>>4)*4 + reg
    const int rbase = bid * 128 + wave * 16 + ((lane >> 4) * 4);
#pragma unroll
    for (int ct = 0; ct < NCT; ct++) {
#pragma unroll
        for (int r = 0; r < 4; r++) {
            H[(size_t)(rbase + r) * NCOL + ct * 16 + (lane & 15)] = f2h_bits(acc[ct][r]);
        }
    }
}

// ---------------------------------------------------------------------------
// FUSED dispatch: blocks [0,GB) = gemm1 (x @ W1 -> fp16 H1, no dis);
//                 blocks [GB,GB+SC) = bucket_scatter (1024 edges/block).
// Independent inputs -> they co-schedule, hiding gemm1 under scatter.
// ---------------------------------------------------------------------------

__global__ __launch_bounds__(512) void gemm1_scatter(const float* __restrict__ X,
                                                     const unsigned short* __restrict__ wh,
                                                     const unsigned short* __restrict__ wl,
                                                     unsigned short* __restrict__ H,
                                                     const int* __restrict__ erow,
                                                     const int* __restrict__ ecol,
                                                     int* __restrict__ gcur,
                                                     int2* __restrict__ temp) {
    __shared__ __align__(16) char smem[65536];  // union: gemm W tiles / scatter hist
    const int tid = threadIdx.x;

    if (blockIdx.x < GB) {
        unsigned short* s_wh = (unsigned short*)smem;
        unsigned short* s_wl = s_wh + 2048 * 8;
        gemm_body<128, false>(X, wh, wl, H, s_wh, s_wl, tid, blockIdx.x);
    } else {
        int* hist = (int*)smem;
        int* rbase = hist + NBUCK;
        const int ebase = (blockIdx.x - GB) * 1024;
        if (tid < NBUCK) hist[tid] = 0;
        __syncthreads();

        const int e0 = ebase + tid;
        const int e1 = ebase + tid + 512;
        const bool v0 = e0 < EDGES;
        const bool v1 = e1 < EDGES;
        int c0 = 0, s0 = 0, b0 = 0, r0 = 0;
        int c1 = 0, s1 = 0, b1 = 0, r1 = 0;
        if (v0) {
            c0 = ecol[e0]; s0 = erow[e0];
            b0 = c0 >> BSHIFT;
            r0 = atomicAdd(&hist[b0], 1);
        }
        if (v1) {
            c1 = ecol[e1]; s1 = erow[e1];
            b1 = c1 >> BSHIFT;
            r1 = atomicAdd(&hist[b1], 1);
        }
        __syncthreads();
        if (tid < NBUCK) {
            int h = hist[tid];
            rbase[tid] = h ? atomicAdd(&gcur[tid], h) : 0;
        }
        __syncthreads();
        if (v0) {
            int2 v; v.x = s0; v.y = c0 & (BNODES - 1);
            temp[(size_t)b0 * BCAP + rbase[b0] + r0] = v;
        }
        if (v1) {
            int2 v; v.x = s1; v.y = c1 & (BNODES - 1);
            temp[(size_t)b1 * BCAP + rbase[b1] + r1] = v;
        }
    }
}

// ---------------------------------------------------------------------------
// gemm2 standalone: h2' = out1 @ W2  (fp16 in/out, no dis)
// ---------------------------------------------------------------------------

__global__ __launch_bounds__(512) void gemm2_kernel(const unsigned short* __restrict__ X,
                                                    const unsigned short* __restrict__ wh,
                                                    const unsigned short* __restrict__ wl,
                                                    unsigned short* __restrict__ H) {
    __shared__ unsigned short s_wh[1024 * 8];
    __shared__ unsigned short s_wl[1024 * 8];
    gemm_body<64, true>(X, wh, wl, H, s_wh, s_wl, threadIdx.x, blockIdx.x);
}

// ---------------------------------------------------------------------------
// CSR build per bucket, inline 196-wide scan (reads gcur sizes)
// ---------------------------------------------------------------------------

__global__ __launch_bounds__(1024) void bucket_build(const int2* __restrict__ temp,
                                                     const int* __restrict__ gcur,
                                                     int* __restrict__ row_start,
                                                     float* __restrict__ dis,
                                                     int* __restrict__ esrc) {
    __shared__ int cnt[BNODES];
    __shared__ int offs[BNODES];
    __shared__ int cur[BNODES];
    __shared__ int ssc[256];
    const int b = blockIdx.x;
    const int tid = threadIdx.x;

    if (tid < 256) ssc[tid] = (tid < NBUCK) ? gcur[tid] : 0;
    __syncthreads();
    for (int d = 1; d < 256; d <<= 1) {
        int x = (tid < 256 && tid >= d) ? ssc[tid - d] : 0;
        __syncthreads();
        if (tid < 256) ssc[tid] += x;
        __syncthreads();
    }
    const int size = gcur[b];
    const int gbase = ssc[b] - size;  // exclusive prefix
    if (b == 0 && tid == 0) row_start[NODES] = EDGES;

    if (tid < BNODES) cnt[tid] = 0;
    __syncthreads();

    for (int i = tid; i < size; i += 1024) {
        int2 v = temp[(size_t)b * BCAP + i];
        atomicAdd(&cnt[v.y], 1);
    }
    __syncthreads();

    if (tid < BNODES) offs[tid] = cnt[tid];
    __syncthreads();
    for (int d = 1; d < BNODES; d <<= 1) {
        int x = 0;
        if (tid < BNODES && tid >= d) x = offs[tid - d];
        __syncthreads();
        if (tid < BNODES) offs[tid] += x;
        __syncthreads();
    }
    if (tid < BNODES) {
        int excl = offs[tid] - cnt[tid];
        cur[tid] = excl;
        int v = b * BNODES + tid;
        if (v < NODES) {
            row_start[v] = gbase + excl;
            dis[v] = rsqrtf((float)(cnt[tid] + 1));  // +1 self-loop
        }
    }
    __syncthreads();

    for (int i = tid; i < size; i += 1024) {
        int2 v = temp[(size_t)b * BCAP + i];
        int pos = gbase + atomicAdd(&cur[v.y], 1);
        esrc[pos] = v.x;
    }
}

// ---------------------------------------------------------------------------
// Aggregation v4 (fp16 H, dis UNFOLDED): per-edge weight dis[src]:
//   OUT[v] = act( dis[v] * ( S_e dis[src_e]*H[src_e] + dis[v]*H[v] ) + b )
// One node per GL-lane group; uint4 full-row gathers; 4-deep unroll;
// next indices AND their dis prefetched.
// ---------------------------------------------------------------------------

template <int C, bool RELU, bool OUT_HALF>
__global__ __launch_bounds__(256, 8) void agg_v4(const unsigned short* __restrict__ H,
                                                 const int* __restrict__ row_start,
                                                 const int* __restrict__ edge_src,
                                                 const float* __restrict__ dis,
                                                 const float* __restrict__ bias,
                                                 void* __restrict__ OUT) {
    constexpr int GL = (C == 128) ? 16 : 8;
    constexpr int GPW = 64 / GL;
    constexpr int RQ = C / 8;  // row length in uint4 (fp16)

    const int lane = threadIdx.x & 63;
    const int sub = lane & (GL - 1);
    const int grp = lane >> ((C == 128) ? 4 : 3);
    const int wid = (blockIdx.x * 256 + threadIdx.x) >> 6;
    const int v = wid * GPW + grp;
    if (v >= NODES) return;

    const uint4* __restrict__ Hq = (const uint4*)H;

    const int e0 = row_start[v];
    const int e1 = row_start[v + 1];
    const float dv = dis[v];

    const float4 ba = ((const float4*)bias)[sub * 2];
    const float4 bb = ((const float4*)bias)[sub * 2 + 1];

    uint4 gs = Hq[(size_t)v * RQ + sub];  // self row

    int i0 = edge_src[min(e0 + 0, EDGES - 1)];
    int i1 = edge_src[min(e0 + 1, EDGES - 1)];
    int i2 = edge_src[min(e0 + 2, EDGES - 1)];
    int i3 = edge_src[min(e0 + 3, EDGES - 1)];
    float d0 = dis[i0], d1 = dis[i1], d2 = dis[i2], d3 = dis[i3];

    float a0, a1, a2, a3, a4, a5, a6, a7;
    {   // self contribution: dv * H[v]
        float2 f0 = h2f2(gs.x), f1 = h2f2(gs.y), f2 = h2f2(gs.z), f3 = h2f2(gs.w);
        a0 = f0.x * dv; a1 = f0.y * dv; a2 = f1.x * dv; a3 = f1.y * dv;
        a4 = f2.x * dv; a5 = f2.y * dv; a6 = f3.x * dv; a7 = f3.y * dv;
    }

    for (int k = e0; k < e1; k += 4) {
        uint4 g0 = Hq[(size_t)i0 * RQ + sub];
        uint4 g1 = Hq[(size_t)i1 * RQ + sub];
        uint4 g2 = Hq[(size_t)i2 * RQ + sub];
        uint4 g3 = Hq[(size_t)i3 * RQ + sub];
        // prefetch next chunk's indices + their dis (hidden under gathers)
        const int n0 = edge_src[min(k + 4, EDGES - 1)];
        const int n1 = edge_src[min(k + 5, EDGES - 1)];
        const int n2 = edge_src[min(k + 6, EDGES - 1)];
        const int n3 = edge_src[min(k + 7, EDGES - 1)];
        const float dn0 = dis[n0], dn1 = dis[n1], dn2 = dis[n2], dn3 = dis[n3];
        // per-edge weights = dis[src] (masked past e1)
        const float w0 = d0;
        const float w1 = (k + 1 < e1) ? d1 : 0.f;
        const float w2 = (k + 2 < e1) ? d2 : 0.f;
        const float w3 = (k + 3 < e1) ? d3 : 0.f;
#define ACC(G, W)                                                        \
        {                                                                \
            float2 f0 = h2f2(G.x), f1 = h2f2(G.y);                       \
            float2 f2 = h2f2(G.z), f3 = h2f2(G.w);                       \
            a0 = fmaf(f0.x, W, a0); a1 = fmaf(f0.y, W, a1);              \
            a2 = fmaf(f1.x, W, a2); a3 = fmaf(f1.y, W, a3);              \
            a4 = fmaf(f2.x, W, a4); a5 = fmaf(f2.y, W, a5);              \
            a6 = fmaf(f3.x, W, a6); a7 = fmaf(f3.y, W, a7);              \
        }
        ACC(g0, w0)
        ACC(g1, w1)
        ACC(g2, w2)
        ACC(g3, w3)
#undef ACC
        i0 = n0; i1 = n1; i2 = n2; i3 = n3;
        d0 = dn0; d1 = dn1; d2 = dn2; d3 = dn3;
    }

    float o0 = fmaf(a0, dv, ba.x);
    float o1 = fmaf(a1, dv, ba.y);
    float o2 = fmaf(a2, dv, ba.z);
    float o3 = fmaf(a3, dv, ba.w);
    float o4 = fmaf(a4, dv, bb.x);
    float o5 = fmaf(a5, dv, bb.y);
    float o6 = fmaf(a6, dv, bb.z);
    float o7 = fmaf(a7, dv, bb.w);
    if constexpr (RELU) {
        o0 = fmaxf(o0, 0.f); o1 = fmaxf(o1, 0.f);
        o2 = fmaxf(o2, 0.f); o3 = fmaxf(o3, 0.f);
        o4 = fmaxf(o4, 0.f); o5 = fmaxf(o5, 0.f);
        o6 = fmaxf(o6, 0.f); o7 = fmaxf(o7, 0.f);
    }

    if constexpr (OUT_HALF) {
        uint4 o;
        o.x = __builtin_bit_cast(unsigned, __float22half2_rn(make_float2(o0, o1)));
        o.y = __builtin_bit_cast(unsigned, __float22half2_rn(make_float2(o2, o3)));
        o.z = __builtin_bit_cast(unsigned, __float22half2_rn(make_float2(o4, o5)));
        o.w = __builtin_bit_cast(unsigned, __float22half2_rn(make_float2(o6, o7)));
        ((uint4*)OUT)[(size_t)v * RQ + sub] = o;
    } else {
        float4 oa, ob;
        oa.x = o0; oa.y = o1; oa.z = o2; oa.w = o3;
        ob.x = o4; ob.y = o5; ob.z = o6; ob.w = o7;
        float* outp = (float*)OUT + (size_t)v * C + sub * 8;
        *(float4*)(outp) = oa;
        *(float4*)(outp + 4) = ob;
    }
}

// ---------------------------------------------------------------------------

extern "C" void kernel_launch(void* const* d_in, const int* in_sizes, int n_in,
                              void* d_out, int out_size, void* d_ws, size_t ws_size,
                              hipStream_t stream) {
    const float* x   = (const float*)d_in[0];
    const int* eidx  = (const int*)d_in[1];
    const float* W1  = (const float*)d_in[2];
    const float* b1  = (const float*)d_in[3];
    const float* W2  = (const float*)d_in[4];
    const float* b2  = (const float*)d_in[5];
    float* out = (float*)d_out;

    const int* erow = eidx;          // sources
    const int* ecol = eidx + EDGES;  // targets

    // workspace carve-up (256B aligned)
    char* w = (char*)d_ws;
    size_t off = 0;
    auto alloc = [&](size_t bytes) -> void* {
        void* p = w + off;
        off += (bytes + 255) & ~(size_t)255;
        return p;
    };
    float* dis     = (float*)alloc((size_t)NODES * 4);
    int*   rowst   = (int*)alloc((size_t)(NODES + 1) * 4);
    int*   esrc    = (int*)alloc((size_t)EDGES * 4);
    int*   gcur    = (int*)alloc(NBUCK * 4);
    int2*  temp    = (int2*)alloc((size_t)NBUCK * BCAP * 8);
    unsigned short* wh1 = (unsigned short*)alloc(2048 * 8 * 2);
    unsigned short* wl1 = (unsigned short*)alloc(2048 * 8 * 2);
    unsigned short* wh2 = (unsigned short*)alloc(1024 * 8 * 2);
    unsigned short* wl2 = (unsigned short*)alloc(1024 * 8 * 2);
    unsigned short* bufA = (unsigned short*)alloc((size_t)NODES * 128 * 2);  // h1 (fp16, no dis)
    unsigned short* bufB = (unsigned short*)alloc((size_t)NODES * 128 * 2);  // out1 fp16
    unsigned short* bufC = (unsigned short*)alloc((size_t)NODES * 64 * 2);   // h2 fp16

    // 1) weight prep + gcur zero
    prep_kernel<<<13, 256, 0, stream>>>(W1, W2, wh1, wl1, wh2, wl2, gcur);

    // 2) FUSED: gemm1 (h1 = x@W1, fp16) || bucket_scatter (independent inputs)
    gemm1_scatter<<<GB + SC, 512, 0, stream>>>(x, wh1, wl1, bufA, erow, ecol, gcur, temp);

    // 3) CSR build (row_start, dis, esrc)
    bucket_build<<<NBUCK, 1024, 0, stream>>>(temp, gcur, rowst, dis, esrc);

    // 4) agg1: out1 = relu(dis_v*(S dis_s*h1[s] + dis_v*h1[v]) + b1)  (fp16)
    agg_v4<128, true, true><<<NODES / 16, 256, 0, stream>>>(bufA, rowst, esrc, dis, b1, bufB);

    // 5) gemm2: h2 = out1 @ W2  (fp16)
    gemm2_kernel<<<GB, 512, 0, stream>>>(bufB, wh2, wl2, bufC);

    // 6) agg2: out = dis_v*(S dis_s*h2[s] + dis_v*h2[v]) + b2  (f32)
    agg_v4<64, false, false><<<NODES / 32, 256, 0, stream>>>(bufC, rowst, esrc, dis, b2, out);
}

// Round 9
// 168.107 us; speedup vs baseline: 3.3257x; 1.0980x over previous
//
#include <hip/hip_runtime.h>
#include <hip/hip_fp16.h>

#define NODES 100000
#define EDGES 1600000

#define BSHIFT 9
#define BNODES 512                                   // nodes per bucket
#define NBUCK ((NODES + BNODES - 1) / BNODES)        // 196
#define BCAP 10240                                   // max edges per bucket (avg 8163)

#define GB 782                                       // gemm1 blocks (128 rows each)
#define SC 1563                                      // scatter blocks (1024 edges each)

typedef __attribute__((ext_vector_type(8))) short short8;
typedef __attribute__((ext_vector_type(8))) _Float16 half8;
typedef __attribute__((ext_vector_type(4))) float f32x4;

// ---------------------------------------------------------------------------
// bf16 / fp16 helpers
// ---------------------------------------------------------------------------
__device__ inline unsigned short f2bf(float f) {
    unsigned u = __builtin_bit_cast(unsigned, f);
    u = u + 0x7fff + ((u >> 16) & 1);
    return (unsigned short)(u >> 16);
}
__device__ inline float bf2f(unsigned short h) {
    unsigned u = ((unsigned)h) << 16;
    return __builtin_bit_cast(float, u);
}
__device__ inline unsigned short f2h_bits(float f) {
    __half h = __float2half_rn(f);
    return __builtin_bit_cast(unsigned short, h);
}
__device__ inline float h2f(unsigned short bits) {
    return __half2float(__builtin_bit_cast(__half, bits));
}
__device__ inline float2 h2f2(unsigned int bits) {
    __half2 h = __builtin_bit_cast(__half2, bits);
    return __half22float2(h);
}

// ---------------------------------------------------------------------------
// prep: blocks 0-7  -> W1 hi/lo bf16 frags (for split-precision gemm1)
//       blocks 8-11 -> W2 fp16 frags (single precision, for fused MFMA matvec)
//       block 12    -> zero gcur
// frag layout (16x16x32): k = kt*32 + (lane>>4)*8 + i, c = ct*16 + (lane&15)
// ---------------------------------------------------------------------------

__global__ __launch_bounds__(256) void prep_kernel(const float* __restrict__ W1,
                                                   const float* __restrict__ W2,
                                                   unsigned short* __restrict__ wh1,
                                                   unsigned short* __restrict__ wl1,
                                                   unsigned short* __restrict__ w2f,
                                                   int* __restrict__ gcur) {
    const int tid = threadIdx.x;
    const int b = blockIdx.x;
    if (b < 8) {
        constexpr int NCT = 8;  // 128/16
        int idx = b * 256 + tid;
        int lane = idx & 63;
        int rem = idx >> 6;
        int ct = rem % NCT;
        int kt = rem / NCT;
        int kbase = kt * 32 + ((lane >> 4) * 8);
        int c = ct * 16 + (lane & 15);
#pragma unroll
        for (int i = 0; i < 8; i++) {
            float v = W1[(size_t)(kbase + i) * 128 + c];
            unsigned short hi = f2bf(v);
            unsigned short lo = f2bf(v - bf2f(hi));
            wh1[(size_t)idx * 8 + i] = hi;
            wl1[(size_t)idx * 8 + i] = lo;
        }
    } else if (b < 12) {
        constexpr int NCT = 4;  // 64/16
        int idx = (b - 8) * 256 + tid;  // [0,1024)
        int lane = idx & 63;
        int rem = idx >> 6;
        int ct = rem % NCT;
        int kt = rem / NCT;
        int kbase = kt * 32 + ((lane >> 4) * 8);
        int c = ct * 16 + (lane & 15);
#pragma unroll
        for (int i = 0; i < 8; i++) {
            w2f[(size_t)idx * 8 + i] = f2h_bits(W2[(size_t)(kbase + i) * 64 + c]);
        }
    } else {
        if (tid < NBUCK) gcur[tid] = 0;
    }
}

// ---------------------------------------------------------------------------
// GEMM1 body via MFMA 16x16x32 bf16, split-precision: H = X @ W1 (fp16 out)
// ---------------------------------------------------------------------------

__device__ __forceinline__ void gemm1_body(const float* __restrict__ X,
                                           const unsigned short* __restrict__ wh,
                                           const unsigned short* __restrict__ wl,
                                           unsigned short* __restrict__ H,
                                           unsigned short* s_wh,
                                           unsigned short* s_wl,
                                           int tid, int bid) {
    constexpr int NCT = 8;
    constexpr int FRAGS = 2048;

    const int wave = tid >> 6;
    const int lane = tid & 63;

    const int row0 = bid * 128 + wave * 16 + (lane & 15);
    const bool active = (bid * 128 + wave * 16) < NODES;  // wave-uniform

    float xs[4][8];
    if (active) {
        const float* xrow = X + (size_t)row0 * 128 + ((lane >> 4) * 8);
#pragma unroll
        for (int kt = 0; kt < 4; kt++) {
            float4 a = *(const float4*)(xrow + kt * 32);
            float4 b = *(const float4*)(xrow + kt * 32 + 4);
            xs[kt][0] = a.x; xs[kt][1] = a.y; xs[kt][2] = a.z; xs[kt][3] = a.w;
            xs[kt][4] = b.x; xs[kt][5] = b.y; xs[kt][6] = b.z; xs[kt][7] = b.w;
        }
    }

#pragma unroll
    for (int j = 0; j < 4; j++) {
        __builtin_amdgcn_global_load_lds((const unsigned int*)((const char*)wh + ((size_t)tid + j * 512) * 16),
                                         (unsigned int*)(s_wh + ((size_t)tid + j * 512) * 8), 16, 0, 0);
        __builtin_amdgcn_global_load_lds((const unsigned int*)((const char*)wl + ((size_t)tid + j * 512) * 16),
                                         (unsigned int*)(s_wl + ((size_t)tid + j * 512) * 8), 16, 0, 0);
    }
    __syncthreads();

    if (!active) return;

    short8 ah[4], al[4];
#pragma unroll
    for (int kt = 0; kt < 4; kt++) {
#pragma unroll
        for (int i = 0; i < 8; i++) {
            unsigned short hi = f2bf(xs[kt][i]);
            unsigned short lo = f2bf(xs[kt][i] - bf2f(hi));
            ah[kt][i] = (short)hi;
            al[kt][i] = (short)lo;
        }
    }

    f32x4 acc[NCT];
#pragma unroll
    for (int ct = 0; ct < NCT; ct++) acc[ct] = (f32x4){0.f, 0.f, 0.f, 0.f};

#pragma unroll
    for (int kt = 0; kt < 4; kt++) {
#pragma unroll
        for (int ct = 0; ct < NCT; ct++) {
            const int fo = ((kt * NCT + ct) * 64 + lane) * 8;
            short8 bh = *(const short8*)&s_wh[fo];
            short8 bl = *(const short8*)&s_wl[fo];
            acc[ct] = __builtin_amdgcn_mfma_f32_16x16x32_bf16(ah[kt], bh, acc[ct], 0, 0, 0);
            acc[ct] = __builtin_amdgcn_mfma_f32_16x16x32_bf16(al[kt], bh, acc[ct], 0, 0, 0);
            acc[ct] = __builtin_amdgcn_mfma_f32_16x16x32_bf16(ah[kt], bl, acc[ct], 0, 0, 0);
        }
    }

    // D layout: col = lane&15, row = (lane>>4)*4 + reg
    const int rbase = bid * 128 + wave * 16 + ((lane >> 4) * 4);
#pragma unroll
    for (int ct = 0; ct < NCT; ct++) {
#pragma unroll
        for (int r = 0; r < 4; r++) {
            H[(size_t)(rbase + r) * 128 + ct * 16 + (lane & 15)] = f2h_bits(acc[ct][r]);
        }
    }
}

// ---------------------------------------------------------------------------
// FUSED dispatch: blocks [0,GB) = gemm1; blocks [GB,GB+SC) = bucket_scatter
// ---------------------------------------------------------------------------

__global__ __launch_bounds__(512) void gemm1_scatter(const float* __restrict__ X,
                                                     const unsigned short* __restrict__ wh,
                                                     const unsigned short* __restrict__ wl,
                                                     unsigned short* __restrict__ H,
                                                     const int* __restrict__ erow,
                                                     const int* __restrict__ ecol,
                                                     int* __restrict__ gcur,
                                                     int2* __restrict__ temp) {
    __shared__ __align__(16) char smem[65536];
    const int tid = threadIdx.x;

    if (blockIdx.x < GB) {
        unsigned short* s_wh = (unsigned short*)smem;
        unsigned short* s_wl = s_wh + 2048 * 8;
        gemm1_body(X, wh, wl, H, s_wh, s_wl, tid, blockIdx.x);
    } else {
        int* hist = (int*)smem;
        int* rbase = hist + NBUCK;
        const int ebase = (blockIdx.x - GB) * 1024;
        if (tid < NBUCK) hist[tid] = 0;
        __syncthreads();

        const int e0 = ebase + tid;
        const int e1 = ebase + tid + 512;
        const bool v0 = e0 < EDGES;
        const bool v1 = e1 < EDGES;
        int c0 = 0, s0 = 0, b0 = 0, r0 = 0;
        int c1 = 0, s1 = 0, b1 = 0, r1 = 0;
        if (v0) {
            c0 = ecol[e0]; s0 = erow[e0];
            b0 = c0 >> BSHIFT;
            r0 = atomicAdd(&hist[b0], 1);
        }
        if (v1) {
            c1 = ecol[e1]; s1 = erow[e1];
            b1 = c1 >> BSHIFT;
            r1 = atomicAdd(&hist[b1], 1);
        }
        __syncthreads();
        if (tid < NBUCK) {
            int h = hist[tid];
            rbase[tid] = h ? atomicAdd(&gcur[tid], h) : 0;
        }
        __syncthreads();
        if (v0) {
            int2 v; v.x = s0; v.y = c0 & (BNODES - 1);
            temp[(size_t)b0 * BCAP + rbase[b0] + r0] = v;
        }
        if (v1) {
            int2 v; v.x = s1; v.y = c1 & (BNODES - 1);
            temp[(size_t)b1 * BCAP + rbase[b1] + r1] = v;
        }
    }
}

// ---------------------------------------------------------------------------
// CSR build per bucket, inline 196-wide scan
// ---------------------------------------------------------------------------

__global__ __launch_bounds__(1024) void bucket_build(const int2* __restrict__ temp,
                                                     const int* __restrict__ gcur,
                                                     int* __restrict__ row_start,
                                                     float* __restrict__ dis,
                                                     int* __restrict__ esrc) {
    __shared__ int cnt[BNODES];
    __shared__ int offs[BNODES];
    __shared__ int cur[BNODES];
    __shared__ int ssc[256];
    const int b = blockIdx.x;
    const int tid = threadIdx.x;

    if (tid < 256) ssc[tid] = (tid < NBUCK) ? gcur[tid] : 0;
    __syncthreads();
    for (int d = 1; d < 256; d <<= 1) {
        int x = (tid < 256 && tid >= d) ? ssc[tid - d] : 0;
        __syncthreads();
        if (tid < 256) ssc[tid] += x;
        __syncthreads();
    }
    const int size = gcur[b];
    const int gbase = ssc[b] - size;  // exclusive prefix
    if (b == 0 && tid == 0) row_start[NODES] = EDGES;

    if (tid < BNODES) cnt[tid] = 0;
    __syncthreads();

    for (int i = tid; i < size; i += 1024) {
        int2 v = temp[(size_t)b * BCAP + i];
        atomicAdd(&cnt[v.y], 1);
    }
    __syncthreads();

    if (tid < BNODES) offs[tid] = cnt[tid];
    __syncthreads();
    for (int d = 1; d < BNODES; d <<= 1) {
        int x = 0;
        if (tid < BNODES && tid >= d) x = offs[tid - d];
        __syncthreads();
        if (tid < BNODES) offs[tid] += x;
        __syncthreads();
    }
    if (tid < BNODES) {
        int excl = offs[tid] - cnt[tid];
        cur[tid] = excl;
        int v = b * BNODES + tid;
        if (v < NODES) {
            row_start[v] = gbase + excl;
            dis[v] = rsqrtf((float)(cnt[tid] + 1));  // +1 self-loop
        }
    }
    __syncthreads();

    for (int i = tid; i < size; i += 1024) {
        int2 v = temp[(size_t)b * BCAP + i];
        int pos = gbase + atomicAdd(&cur[v.y], 1);
        esrc[pos] = v.x;
    }
}

// ---------------------------------------------------------------------------
// FUSED agg1 + gemm2:
//   phase A (gather, = agg_v4<128>): out1[v] = relu(dv*(S dis_s*h1[s] + dv*h1[v]) + b1)
//            -> f32 LDS h_lds[16][132] (padded: 2-way banks = free)
//   phase B (MFMA f16): h2[v] = out1[v] @ W2  (W2 fp16 frags staged in LDS)
// 16 nodes/block, GL=16 lanes/node; exact grid 6250 (barrier-safe, no tail).
// ---------------------------------------------------------------------------

__global__ __launch_bounds__(256, 6) void agg1_gemm2(const unsigned short* __restrict__ H,
                                                     const int* __restrict__ row_start,
                                                     const int* __restrict__ edge_src,
                                                     const float* __restrict__ dis,
                                                     const float* __restrict__ b1,
                                                     const unsigned short* __restrict__ w2f,
                                                     unsigned short* __restrict__ H2) {
    __shared__ float h_lds[16][132];            // 8.25 KB (stride 132: aligned + 2-way)
    __shared__ unsigned short s_w2[1024 * 8];   // 16 KB fp16 W2 frags

    const int tid = threadIdx.x;
    const int lane = tid & 63;
    const int sub = lane & 15;
    const int grp = lane >> 4;
    const int nl = (tid >> 6) * 4 + grp;        // node_local in [0,16)
    const int v = blockIdx.x * 16 + nl;

    // stage W2 frags (16KB, linear) — latency hides under the gather phase
#pragma unroll
    for (int j = 0; j < 4; j++) {
        __builtin_amdgcn_global_load_lds((const unsigned int*)((const char*)w2f + ((size_t)tid + j * 256) * 16),
                                         (unsigned int*)(s_w2 + ((size_t)tid + j * 256) * 8), 16, 0, 0);
    }

    // ---- phase A: gather (identical structure to agg_v4<128>) ----
    const uint4* __restrict__ Hq = (const uint4*)H;
    const int e0 = row_start[v];
    const int e1 = row_start[v + 1];
    const float dv = dis[v];

    const float4 ba = ((const float4*)b1)[sub * 2];
    const float4 bb = ((const float4*)b1)[sub * 2 + 1];

    uint4 gs = Hq[(size_t)v * 16 + sub];  // self row

    int i0 = edge_src[min(e0 + 0, EDGES - 1)];
    int i1 = edge_src[min(e0 + 1, EDGES - 1)];
    int i2 = edge_src[min(e0 + 2, EDGES - 1)];
    int i3 = edge_src[min(e0 + 3, EDGES - 1)];
    float d0 = dis[i0], d1 = dis[i1], d2 = dis[i2], d3 = dis[i3];

    float a0, a1, a2, a3, a4, a5, a6, a7;
    {
        float2 f0 = h2f2(gs.x), f1 = h2f2(gs.y), f2 = h2f2(gs.z), f3 = h2f2(gs.w);
        a0 = f0.x * dv; a1 = f0.y * dv; a2 = f1.x * dv; a3 = f1.y * dv;
        a4 = f2.x * dv; a5 = f2.y * dv; a6 = f3.x * dv; a7 = f3.y * dv;
    }

    for (int k = e0; k < e1; k += 4) {
        uint4 g0 = Hq[(size_t)i0 * 16 + sub];
        uint4 g1 = Hq[(size_t)i1 * 16 + sub];
        uint4 g2 = Hq[(size_t)i2 * 16 + sub];
        uint4 g3 = Hq[(size_t)i3 * 16 + sub];
        const int n0 = edge_src[min(k + 4, EDGES - 1)];
        const int n1 = edge_src[min(k + 5, EDGES - 1)];
        const int n2 = edge_src[min(k + 6, EDGES - 1)];
        const int n3 = edge_src[min(k + 7, EDGES - 1)];
        const float dn0 = dis[n0], dn1 = dis[n1], dn2 = dis[n2], dn3 = dis[n3];
        const float w0 = d0;
        const float w1 = (k + 1 < e1) ? d1 : 0.f;
        const float w2 = (k + 2 < e1) ? d2 : 0.f;
        const float w3 = (k + 3 < e1) ? d3 : 0.f;
#define ACC(G, W)                                                        \
        {                                                                \
            float2 f0 = h2f2(G.x), f1 = h2f2(G.y);                       \
            float2 f2 = h2f2(G.z), f3 = h2f2(G.w);                       \
            a0 = fmaf(f0.x, W, a0); a1 = fmaf(f0.y, W, a1);              \
            a2 = fmaf(f1.x, W, a2); a3 = fmaf(f1.y, W, a3);              \
            a4 = fmaf(f2.x, W, a4); a5 = fmaf(f2.y, W, a5);              \
            a6 = fmaf(f3.x, W, a6); a7 = fmaf(f3.y, W, a7);              \
        }
        ACC(g0, w0)
        ACC(g1, w1)
        ACC(g2, w2)
        ACC(g3, w3)
#undef ACC
        i0 = n0; i1 = n1; i2 = n2; i3 = n3;
        d0 = dn0; d1 = dn1; d2 = dn2; d3 = dn3;
    }

    // out1 epilogue -> LDS (f32, full precision, relu'd)
    {
        float4 oa, ob;
        oa.x = fmaxf(fmaf(a0, dv, ba.x), 0.f);
        oa.y = fmaxf(fmaf(a1, dv, ba.y), 0.f);
        oa.z = fmaxf(fmaf(a2, dv, ba.z), 0.f);
        oa.w = fmaxf(fmaf(a3, dv, ba.w), 0.f);
        ob.x = fmaxf(fmaf(a4, dv, bb.x), 0.f);
        ob.y = fmaxf(fmaf(a5, dv, bb.y), 0.f);
        ob.z = fmaxf(fmaf(a6, dv, bb.z), 0.f);
        ob.w = fmaxf(fmaf(a7, dv, bb.w), 0.f);
        *(float4*)&h_lds[nl][sub * 8] = oa;
        *(float4*)&h_lds[nl][sub * 8 + 4] = ob;
    }
    __syncthreads();  // h_lds ready + W2 frags staged (vmcnt drained)

    // ---- phase B: MFMA f16 matvec, wave ct = wave id, 4 MFMA ----
    const int ct = tid >> 6;
    f32x4 acc = (f32x4){0.f, 0.f, 0.f, 0.f};
#pragma unroll
    for (int kt = 0; kt < 4; kt++) {
        const int arow = lane & 15;
        const int acol = (lane >> 4) * 8 + kt * 32;
        float4 pa = *(const float4*)&h_lds[arow][acol];
        float4 pb = *(const float4*)&h_lds[arow][acol + 4];
        half8 af;
        af[0] = (_Float16)pa.x; af[1] = (_Float16)pa.y;
        af[2] = (_Float16)pa.z; af[3] = (_Float16)pa.w;
        af[4] = (_Float16)pb.x; af[5] = (_Float16)pb.y;
        af[6] = (_Float16)pb.z; af[7] = (_Float16)pb.w;
        half8 bf = *(const half8*)&s_w2[((kt * 4 + ct) * 64 + lane) * 8];
        acc = __builtin_amdgcn_mfma_f32_16x16x32_f16(af, bf, acc, 0, 0, 0);
    }

    // D layout: col = lane&15 (out ch ct*16+col), row = (lane>>4)*4 + reg (node)
    const int rbase = blockIdx.x * 16 + ((lane >> 4) * 4);
#pragma unroll
    for (int r = 0; r < 4; r++) {
        H2[(size_t)(rbase + r) * 64 + ct * 16 + (lane & 15)] = f2h_bits(acc[r]);
    }
}

// ---------------------------------------------------------------------------
// Aggregation layer 2 (64ch fp16 in, f32 out), dis-weighted edges
// ---------------------------------------------------------------------------

__global__ __launch_bounds__(256, 8) void agg_l2(const unsigned short* __restrict__ H,
                                                 const int* __restrict__ row_start,
                                                 const int* __restrict__ edge_src,
                                                 const float* __restrict__ dis,
                                                 const float* __restrict__ bias,
                                                 float* __restrict__ OUT) {
    constexpr int RQ = 8;  // row length in uint4

    const int lane = threadIdx.x & 63;
    const int sub = lane & 7;
    const int grp = lane >> 3;
    const int wid = (blockIdx.x * 256 + threadIdx.x) >> 6;
    const int v = wid * 8 + grp;

    const uint4* __restrict__ Hq = (const uint4*)H;

    const int e0 = row_start[v];
    const int e1 = row_start[v + 1];
    const float dv = dis[v];

    const float4 ba = ((const float4*)bias)[sub * 2];
    const float4 bb = ((const float4*)bias)[sub * 2 + 1];

    uint4 gs = Hq[(size_t)v * RQ + sub];

    int i0 = edge_src[min(e0 + 0, EDGES - 1)];
    int i1 = edge_src[min(e0 + 1, EDGES - 1)];
    int i2 = edge_src[min(e0 + 2, EDGES - 1)];
    int i3 = edge_src[min(e0 + 3, EDGES - 1)];
    float d0 = dis[i0], d1 = dis[i1], d2 = dis[i2], d3 = dis[i3];

    float a0, a1, a2, a3, a4, a5, a6, a7;
    {
        float2 f0 = h2f2(gs.x), f1 = h2f2(gs.y), f2 = h2f2(gs.z), f3 = h2f2(gs.w);
        a0 = f0.x * dv; a1 = f0.y * dv; a2 = f1.x * dv; a3 = f1.y * dv;
        a4 = f2.x * dv; a5 = f2.y * dv; a6 = f3.x * dv; a7 = f3.y * dv;
    }

    for (int k = e0; k < e1; k += 4) {
        uint4 g0 = Hq[(size_t)i0 * RQ + sub];
        uint4 g1 = Hq[(size_t)i1 * RQ + sub];
        uint4 g2 = Hq[(size_t)i2 * RQ + sub];
        uint4 g3 = Hq[(size_t)i3 * RQ + sub];
        const int n0 = edge_src[min(k + 4, EDGES - 1)];
        const int n1 = edge_src[min(k + 5, EDGES - 1)];
        const int n2 = edge_src[min(k + 6, EDGES - 1)];
        const int n3 = edge_src[min(k + 7, EDGES - 1)];
        const float dn0 = dis[n0], dn1 = dis[n1], dn2 = dis[n2], dn3 = dis[n3];
        const float w0 = d0;
        const float w1 = (k + 1 < e1) ? d1 : 0.f;
        const float w2 = (k + 2 < e1) ? d2 : 0.f;
        const float w3 = (k + 3 < e1) ? d3 : 0.f;
#define ACC(G, W)                                                        \
        {                                                                \
            float2 f0 = h2f2(G.x), f1 = h2f2(G.y);                       \
            float2 f2 = h2f2(G.z), f3 = h2f2(G.w);                       \
            a0 = fmaf(f0.x, W, a0); a1 = fmaf(f0.y, W, a1);              \
            a2 = fmaf(f1.x, W, a2); a3 = fmaf(f1.y, W, a3);              \
            a4 = fmaf(f2.x, W, a4); a5 = fmaf(f2.y, W, a5);              \
            a6 = fmaf(f3.x, W, a6); a7 = fmaf(f3.y, W, a7);              \
        }
        ACC(g0, w0)
        ACC(g1, w1)
        ACC(g2, w2)
        ACC(g3, w3)
#undef ACC
        i0 = n0; i1 = n1; i2 = n2; i3 = n3;
        d0 = dn0; d1 = dn1; d2 = dn2; d3 = dn3;
    }

    float4 oa, ob;
    oa.x = fmaf(a0, dv, ba.x); oa.y = fmaf(a1, dv, ba.y);
    oa.z = fmaf(a2, dv, ba.z); oa.w = fmaf(a3, dv, ba.w);
    ob.x = fmaf(a4, dv, bb.x); ob.y = fmaf(a5, dv, bb.y);
    ob.z = fmaf(a6, dv, bb.z); ob.w = fmaf(a7, dv, bb.w);
    float* outp = OUT + (size_t)v * 64 + sub * 8;
    *(float4*)(outp) = oa;
    *(float4*)(outp + 4) = ob;
}

// ---------------------------------------------------------------------------

extern "C" void kernel_launch(void* const* d_in, const int* in_sizes, int n_in,
                              void* d_out, int out_size, void* d_ws, size_t ws_size,
                              hipStream_t stream) {
    const float* x   = (const float*)d_in[0];
    const int* eidx  = (const int*)d_in[1];
    const float* W1  = (const float*)d_in[2];
    const float* b1  = (const float*)d_in[3];
    const float* W2  = (const float*)d_in[4];
    const float* b2  = (const float*)d_in[5];
    float* out = (float*)d_out;

    const int* erow = eidx;          // sources
    const int* ecol = eidx + EDGES;  // targets

    // workspace carve-up (256B aligned)
    char* w = (char*)d_ws;
    size_t off = 0;
    auto alloc = [&](size_t bytes) -> void* {
        void* p = w + off;
        off += (bytes + 255) & ~(size_t)255;
        return p;
    };
    float* dis     = (float*)alloc((size_t)NODES * 4);
    int*   rowst   = (int*)alloc((size_t)(NODES + 1) * 4);
    int*   esrc    = (int*)alloc((size_t)EDGES * 4);
    int*   gcur    = (int*)alloc(NBUCK * 4);
    int2*  temp    = (int2*)alloc((size_t)NBUCK * BCAP * 8);
    unsigned short* wh1 = (unsigned short*)alloc(2048 * 8 * 2);
    unsigned short* wl1 = (unsigned short*)alloc(2048 * 8 * 2);
    unsigned short* w2f = (unsigned short*)alloc(1024 * 8 * 2);
    unsigned short* bufA = (unsigned short*)alloc((size_t)NODES * 128 * 2);  // h1 (fp16)
    unsigned short* bufC = (unsigned short*)alloc((size_t)NODES * 64 * 2);   // h2 (fp16)

    // 1) weight prep + gcur zero
    prep_kernel<<<13, 256, 0, stream>>>(W1, W2, wh1, wl1, w2f, gcur);

    // 2) FUSED: gemm1 (h1 = x@W1, fp16) || bucket_scatter
    gemm1_scatter<<<GB + SC, 512, 0, stream>>>(x, wh1, wl1, bufA, erow, ecol, gcur, temp);

    // 3) CSR build (row_start, dis, esrc)
    bucket_build<<<NBUCK, 1024, 0, stream>>>(temp, gcur, rowst, dis, esrc);

    // 4) FUSED agg1 + gemm2: h2 = relu(dis*(S dis_s h1) + b1) @ W2  (fp16)
    agg1_gemm2<<<NODES / 16, 256, 0, stream>>>(bufA, rowst, esrc, dis, b1, w2f, bufC);

    // 5) agg2: out = dis*(S dis_s h2 + dis_v h2[v]) + b2  (f32)
    agg_l2<<<NODES / 32, 256, 0, stream>>>(bufC, rowst, esrc, dis, b2, out);
}